// Round 1
// baseline (1367.565 us; speedup 1.0000x reference)
//
#include <hip/hip_runtime.h>
#include <hip/hip_bf16.h>

#define BS 512
#define LL 128
#define DD 512
#define KK 30
#define GG 8
#define EE 2048
#define HH 1024
#define NROWS (BS*KK)   // 15360
#define NG (BS/GG)      // 64

__device__ __forceinline__ unsigned short f2bf(float f){
  unsigned int x = __float_as_uint(f);
  x = (x + 0x7FFFu + ((x >> 16) & 1u)) >> 16;   // round-to-nearest-even
  return (unsigned short)x;
}
__device__ __forceinline__ float bf2f(unsigned short u){
  return __uint_as_float(((unsigned int)u) << 16);
}

// ---------------------------------------------------------------------------
// Kernel 1: per-batch eos/argmax, lengths, masked attention row, top-30 (JAX
// tie-break: descending value, smaller index wins ties).
// ---------------------------------------------------------------------------
__global__ __launch_bounds__(128) void k_prep(const float* __restrict__ atten,
                                              const int* __restrict__ text,
                                              int* __restrict__ idx,
                                              int* __restrict__ lensk){
  const int b = blockIdx.x;
  const int t = threadIdx.x;          // 128 threads
  __shared__ float v[128];
  __shared__ int   vi[128];
  __shared__ float row[128];
  __shared__ int   s_eos;

  const int tok = text[b*LL + t];

  // eos = argmax(text row), first occurrence of max
  v[t] = (float)tok; vi[t] = t; __syncthreads();
  for(int s = 64; s > 0; s >>= 1){
    if(t < s){
      if(v[t+s] > v[t] || (v[t+s] == v[t] && vi[t+s] < vi[t])){ v[t] = v[t+s]; vi[t] = vi[t+s]; }
    }
    __syncthreads();
  }
  if(t == 0) s_eos = vi[0];
  __syncthreads();
  const int eos = s_eos;

  // lengths = nnz(text) - 2 ; lensk = int(min(lengths, K))
  v[t] = (tok != 0) ? 1.0f : 0.0f; __syncthreads();
  for(int s = 64; s > 0; s >>= 1){ if(t < s) v[t] += v[t+s]; __syncthreads(); }
  if(t == 0) lensk[b] = (int)fminf(v[0] - 2.0f, (float)KK);

  // row = att[b, eos, :] * mask   with att[.,.,0] = att[.,.,eos] = -1
  float r = (t == 0 || t == eos) ? -1.0f : atten[(size_t)b*LL*LL + (size_t)eos*LL + t];
  if(tok == 0) r = 0.0f;
  row[t] = r; __syncthreads();

  // top-30 selection (max value, smaller index on tie)
  for(int k = 0; k < KK; k++){
    v[t] = row[t]; vi[t] = t; __syncthreads();
    for(int s = 64; s > 0; s >>= 1){
      if(t < s){
        if(v[t+s] > v[t] || (v[t+s] == v[t] && vi[t+s] < vi[t])){ v[t] = v[t+s]; vi[t] = vi[t+s]; }
      }
      __syncthreads();
    }
    if(t == 0){ idx[b*KK + k] = vi[0]; row[vi[0]] = -3.0f; }
    __syncthreads();
  }
}

// ---------------------------------------------------------------------------
// Kernel 2: gather feats rows; write l2-normed row (bf16) for the MLP path and
// the 8 expert dot-products h (raw feats) for the dlp path.
// ---------------------------------------------------------------------------
__global__ __launch_bounds__(128) void k_gather(const float* __restrict__ features,
                                                const float* __restrict__ dlp_w,
                                                const float* __restrict__ dlp_b,
                                                const int* __restrict__ idx,
                                                unsigned short* __restrict__ nfeats,
                                                float* __restrict__ hval){
  const int r = blockIdx.x;           // b*K + k
  const int b = r / KK;
  const int t = threadIdx.x;          // 128 threads, 4 elems each
  const int l = idx[r];

  const float4 v = ((const float4*)features)[((size_t)b*LL + l)*(DD/4) + t];
  float ss = v.x*v.x + v.y*v.y + v.z*v.z + v.w*v.w;
  float hg[GG];
#pragma unroll
  for(int g = 0; g < GG; g++){
    const float4 w = ((const float4*)dlp_w)[g*(DD/4) + t];
    hg[g] = v.x*w.x + v.y*w.y + v.z*w.z + v.w*w.w;
  }
#pragma unroll
  for(int off = 32; off > 0; off >>= 1){
    ss += __shfl_down(ss, off);
#pragma unroll
    for(int g = 0; g < GG; g++) hg[g] += __shfl_down(hg[g], off);
  }
  __shared__ float red[2][9];
  __shared__ float s_rn;
  const int wave = t >> 6, lane = t & 63;
  if(lane == 0){
    red[wave][0] = ss;
#pragma unroll
    for(int g = 0; g < GG; g++) red[wave][1+g] = hg[g];
  }
  __syncthreads();
  if(t == 0) s_rn = 1.0f / (sqrtf(red[0][0] + red[1][0]) + 1e-8f);
  if(t < GG) hval[(size_t)r*GG + t] = red[0][1+t] + red[1][1+t] + dlp_b[t];
  __syncthreads();
  const float rn = s_rn;
  ushort4 u;
  u.x = f2bf(v.x*rn); u.y = f2bf(v.y*rn); u.z = f2bf(v.z*rn); u.w = f2bf(v.w*rn);
  ((ushort4*)nfeats)[(size_t)r*(DD/4) + t] = u;
}

// ---------------------------------------------------------------------------
// Kernel 3: grouped-expert linear  yg[n,g,:] = h[n,g,:] @ dlp_lw + dlp_lb
// written to nb[n*8+g, :] (scatter mapping b = n*8+g).
// ---------------------------------------------------------------------------
__global__ __launch_bounds__(256) void k_dlp(const float* __restrict__ hval,
                                             const float* __restrict__ dlp_lw,
                                             const float* __restrict__ dlp_lb,
                                             float* __restrict__ nb){
  const int et = blockIdx.x;          // 16 tiles of 128 cols
  const int n  = blockIdx.y;          // 64 groups
  const int tid = threadIdx.x;
  __shared__ float hs[GG][GG*KK];     // [8][240]
  for(int i = tid; i < GG*GG*KK; i += 256){
    const int g = i / (GG*KK), tt = i % (GG*KK);
    const int m = tt / KK, kq = tt % KK;
    hs[g][tt] = hval[(size_t)(((n*GG + m)*KK) + kq)*GG + g];
  }
  __syncthreads();
  const int h = tid >> 7, c = tid & 127;
  const int e = et*128 + c;
  float acc[4] = {0.f, 0.f, 0.f, 0.f};
#pragma unroll 4
  for(int k = 0; k < GG*KK; k++){
    const float w = dlp_lw[(size_t)k*EE + e];
#pragma unroll
    for(int rr = 0; rr < 4; rr++) acc[rr] += hs[h*4 + rr][k] * w;
  }
  const float lb = dlp_lb[e];
#pragma unroll
  for(int rr = 0; rr < 4; rr++)
    nb[(size_t)(n*GG + h*4 + rr)*EE + e] = acc[rr] + lb;
}

// ---------------------------------------------------------------------------
// Kernel 4: l2-normalize nb rows in place: x / (sqrt(sum x^2) + 1e-8)
// ---------------------------------------------------------------------------
__global__ __launch_bounds__(256) void k_l2nb(float* __restrict__ nb){
  const int b = blockIdx.x, t = threadIdx.x;
  float4* p = (float4*)(nb + (size_t)b*EE);
  float4 a = p[t], c = p[t + 256];
  float ss = a.x*a.x + a.y*a.y + a.z*a.z + a.w*a.w
           + c.x*c.x + c.y*c.y + c.z*c.z + c.w*c.w;
#pragma unroll
  for(int off = 32; off > 0; off >>= 1) ss += __shfl_down(ss, off);
  __shared__ float red[4];
  __shared__ float s_rn;
  if((t & 63) == 0) red[t >> 6] = ss;
  __syncthreads();
  if(t == 0) s_rn = 1.0f / (sqrtf(red[0] + red[1] + red[2] + red[3]) + 1e-8f);
  __syncthreads();
  const float rn = s_rn;
  a.x *= rn; a.y *= rn; a.z *= rn; a.w *= rn;
  c.x *= rn; c.y *= rn; c.z *= rn; c.w *= rn;
  p[t] = a; p[t + 256] = c;
}

// ---------------------------------------------------------------------------
// Kernel 5: GEMM1  x1 = nfeats[15360,512] @ w1[512,1024] + b1   (bf16 out)
// 64x128 tile, 256 threads, 4x8 micro-tile, BK=16.
// ---------------------------------------------------------------------------
__global__ __launch_bounds__(256) void k_gemm1(const unsigned short* __restrict__ nfeats,
                                               const float* __restrict__ w1,
                                               const float* __restrict__ b1,
                                               unsigned short* __restrict__ x1){
  const int ct = blockIdx.x;          // 8 col tiles of 128
  const int rb = blockIdx.y;          // 240 row tiles of 64
  const int tid = threadIdx.x;
  const int ty = tid >> 4, tx = tid & 15;   // rows ty*4 (64), cols tx*8 (128)
  __shared__ float As[16][68];        // k-major (transposed), 272B stride
  __shared__ float Bs[16][132];       // 528B stride
  float acc[4][8];
#pragma unroll
  for(int i = 0; i < 4; i++)
#pragma unroll
    for(int j = 0; j < 8; j++) acc[i][j] = 0.f;

  const int arow = tid >> 2;          // 0..63
  const int akq  = (tid & 3) * 4;     // 0,4,8,12

  for(int k0 = 0; k0 < DD; k0 += 16){
    const ushort4 ua = *(const ushort4*)(nfeats + (size_t)(rb*64 + arow)*DD + k0 + akq);
    As[akq+0][arow] = bf2f(ua.x);
    As[akq+1][arow] = bf2f(ua.y);
    As[akq+2][arow] = bf2f(ua.z);
    As[akq+3][arow] = bf2f(ua.w);
#pragma unroll
    for(int j = 0; j < 8; j++){
      const int i2 = tid + j*256;
      const int kk = i2 >> 7, c = i2 & 127;
      Bs[kk][c] = w1[(size_t)(k0 + kk)*HH + ct*128 + c];
    }
    __syncthreads();
#pragma unroll
    for(int kk = 0; kk < 16; kk++){
      const float4 a = *(const float4*)&As[kk][ty*4];
      const float4 p = *(const float4*)&Bs[kk][tx*8];
      const float4 q = *(const float4*)&Bs[kk][tx*8 + 4];
      const float av[4] = {a.x, a.y, a.z, a.w};
      const float bv[8] = {p.x, p.y, p.z, p.w, q.x, q.y, q.z, q.w};
#pragma unroll
      for(int i = 0; i < 4; i++)
#pragma unroll
        for(int j = 0; j < 8; j++) acc[i][j] += av[i]*bv[j];
    }
    __syncthreads();
  }

  float bb[8];
#pragma unroll
  for(int j = 0; j < 8; j++) bb[j] = b1[ct*128 + tx*8 + j];
#pragma unroll
  for(int i = 0; i < 4; i++){
    const int rowg = rb*64 + ty*4 + i;
    ushort4 u0, u1;
    u0.x = f2bf(acc[i][0] + bb[0]); u0.y = f2bf(acc[i][1] + bb[1]);
    u0.z = f2bf(acc[i][2] + bb[2]); u0.w = f2bf(acc[i][3] + bb[3]);
    u1.x = f2bf(acc[i][4] + bb[4]); u1.y = f2bf(acc[i][5] + bb[5]);
    u1.z = f2bf(acc[i][6] + bb[6]); u1.w = f2bf(acc[i][7] + bb[7]);
    ushort4* dst = (ushort4*)(x1 + (size_t)rowg*HH + ct*128 + tx*8);
    dst[0] = u0; dst[1] = u1;
  }
}

// ---------------------------------------------------------------------------
// Kernel 6: BN stats, deterministic two-stage (per 64-row block partials).
// ---------------------------------------------------------------------------
__global__ __launch_bounds__(256) void k_bnstat(const unsigned short* __restrict__ x1,
                                                float* __restrict__ psum,
                                                float* __restrict__ psq){
  const int rb = blockIdx.x, tid = threadIdx.x;   // 240 x 256
  float s[4] = {0,0,0,0}, q[4] = {0,0,0,0};
  for(int r = 0; r < 64; r++){
    const ushort4 u = *(const ushort4*)(x1 + (size_t)(rb*64 + r)*HH + tid*4);
    const float f0 = bf2f(u.x), f1 = bf2f(u.y), f2 = bf2f(u.z), f3 = bf2f(u.w);
    s[0] += f0; q[0] += f0*f0;
    s[1] += f1; q[1] += f1*f1;
    s[2] += f2; q[2] += f2*f2;
    s[3] += f3; q[3] += f3*f3;
  }
#pragma unroll
  for(int j = 0; j < 4; j++){
    psum[(size_t)rb*HH + tid*4 + j] = s[j];
    psq [(size_t)rb*HH + tid*4 + j] = q[j];
  }
}

__global__ __launch_bounds__(256) void k_bnfin(const float* __restrict__ psum,
                                               const float* __restrict__ psq,
                                               const float* __restrict__ bn_g,
                                               const float* __restrict__ bn_b,
                                               float* __restrict__ sc,
                                               float* __restrict__ sh){
  const int c = blockIdx.x*256 + threadIdx.x;     // 4 x 256 = 1024
  float s = 0.f, q = 0.f;
  for(int i = 0; i < 240; i++){ s += psum[(size_t)i*HH + c]; q += psq[(size_t)i*HH + c]; }
  const float mu  = s * (1.0f/NROWS);
  const float var = q * (1.0f/NROWS) - mu*mu;
  const float sv  = bn_g[c] / sqrtf(var + 1e-5f);
  sc[c] = sv;
  sh[c] = bn_b[c] - mu*sv;
}

// ---------------------------------------------------------------------------
// Kernel 7: GEMM2 fused with BN+ReLU on A-load, per-batch max-pool epilogue,
// + b2 + nb.  One block = one batch (30 rows padded to 32) x 128 cols.
// ---------------------------------------------------------------------------
__global__ __launch_bounds__(128) void k_gemm2pool(const unsigned short* __restrict__ x1,
                                                   const float* __restrict__ w2,
                                                   const float* __restrict__ b2,
                                                   const float* __restrict__ sc,
                                                   const float* __restrict__ sh,
                                                   const float* __restrict__ nb,
                                                   const int* __restrict__ lensk,
                                                   float* __restrict__ out){
  const int ct = blockIdx.x;          // 16 col tiles of 128
  const int b  = blockIdx.y;          // 512 batches
  const int tid = threadIdx.x;
  const int ty = tid >> 4, tx = tid & 15;  // rows ty*4 (32), cols tx*8 (128)
  __shared__ float As[16][36];        // k-major, 144B stride
  __shared__ float Bs[16][132];
  __shared__ float pool[32][132];
  float acc[4][8];
#pragma unroll
  for(int i = 0; i < 4; i++)
#pragma unroll
    for(int j = 0; j < 8; j++) acc[i][j] = 0.f;

  const int arow = tid >> 2;          // 0..31
  const int akq  = (tid & 3) * 4;

  for(int k0 = 0; k0 < HH; k0 += 16){
    if(arow < KK){
      const ushort4 ua = *(const ushort4*)(x1 + (size_t)(b*KK + arow)*HH + k0 + akq);
      const float f[4] = {bf2f(ua.x), bf2f(ua.y), bf2f(ua.z), bf2f(ua.w)};
#pragma unroll
      for(int j = 0; j < 4; j++){
        const int k = k0 + akq + j;
        As[akq+j][arow] = fmaxf(f[j]*sc[k] + sh[k], 0.0f);   // BN + ReLU
      }
    } else {
#pragma unroll
      for(int j = 0; j < 4; j++) As[akq+j][arow] = 0.0f;
    }
#pragma unroll
    for(int j = 0; j < 16; j++){
      const int i2 = tid + j*128;
      const int kk = i2 >> 7, c = i2 & 127;
      Bs[kk][c] = w2[(size_t)(k0 + kk)*EE + ct*128 + c];
    }
    __syncthreads();
#pragma unroll
    for(int kk = 0; kk < 16; kk++){
      const float4 a = *(const float4*)&As[kk][ty*4];
      const float4 p = *(const float4*)&Bs[kk][tx*8];
      const float4 q = *(const float4*)&Bs[kk][tx*8 + 4];
      const float av[4] = {a.x, a.y, a.z, a.w};
      const float bv[8] = {p.x, p.y, p.z, p.w, q.x, q.y, q.z, q.w};
#pragma unroll
      for(int i = 0; i < 4; i++)
#pragma unroll
        for(int j = 0; j < 8; j++) acc[i][j] += av[i]*bv[j];
    }
    __syncthreads();
  }

#pragma unroll
  for(int i = 0; i < 4; i++){
    *(float4*)&pool[ty*4+i][tx*8]     = make_float4(acc[i][0], acc[i][1], acc[i][2], acc[i][3]);
    *(float4*)&pool[ty*4+i][tx*8 + 4] = make_float4(acc[i][4], acc[i][5], acc[i][6], acc[i][7]);
  }
  __syncthreads();

  const int lk = lensk[b];
  float m = __uint_as_float(0xff800000u);   // -inf
  for(int rr = 0; rr < lk; rr++) m = fmaxf(m, pool[rr][tid]);
  const int gc = ct*128 + tid;
  out[(size_t)b*EE + gc] = m + b2[gc] + nb[(size_t)b*EE + gc];
}

// ---------------------------------------------------------------------------
extern "C" void kernel_launch(void* const* d_in, const int* in_sizes, int n_in,
                              void* d_out, int out_size, void* d_ws, size_t ws_size,
                              hipStream_t stream){
  const float* features = (const float*)d_in[0];
  const float* atten    = (const float*)d_in[1];
  const int*   text     = (const int*)  d_in[2];
  // d_in[3] = pid : repeat(arange(64), 8) -> groups are consecutive blocks of 8
  const float* dlp_w    = (const float*)d_in[4];
  const float* dlp_b    = (const float*)d_in[5];
  const float* dlp_lw   = (const float*)d_in[6];
  const float* dlp_lb   = (const float*)d_in[7];
  const float* w1       = (const float*)d_in[8];
  const float* b1       = (const float*)d_in[9];
  const float* bn_g     = (const float*)d_in[10];
  const float* bn_b     = (const float*)d_in[11];
  const float* w2       = (const float*)d_in[12];
  const float* b2       = (const float*)d_in[13];
  float* out = (float*)d_out;

  char* ws = (char*)d_ws;
  int*            idx    = (int*)(ws + 0);                  //   61,440
  int*            lensk  = (int*)(ws + 61440);              //    2,048
  float*          hval   = (float*)(ws + 63488);            //  491,520
  unsigned short* nfeats = (unsigned short*)(ws + 555008);  // 15,728,640
  unsigned short* x1     = (unsigned short*)(ws + 16283648);// 31,457,280
  float*          nb     = (float*)(ws + 47740928);         //  4,194,304
  float*          psum   = (float*)(ws + 51935232);         //    983,040
  float*          psq    = (float*)(ws + 52918272);         //    983,040
  float*          sc     = (float*)(ws + 53901312);         //    4,096
  float*          sh     = (float*)(ws + 53905408);         //    4,096  -> end 53,909,504

  k_prep<<<BS, 128, 0, stream>>>(atten, text, idx, lensk);
  k_gather<<<NROWS, 128, 0, stream>>>(features, dlp_w, dlp_b, idx, nfeats, hval);
  k_dlp<<<dim3(16, NG), 256, 0, stream>>>(hval, dlp_lw, dlp_lb, nb);
  k_l2nb<<<BS, 256, 0, stream>>>(nb);
  k_gemm1<<<dim3(8, 240), 256, 0, stream>>>(nfeats, w1, b1, x1);
  k_bnstat<<<240, 256, 0, stream>>>(x1, psum, psq);
  k_bnfin<<<4, 256, 0, stream>>>(psum, psq, bn_g, bn_b, sc, sh);
  k_gemm2pool<<<dim3(16, BS), 128, 0, stream>>>(x1, w2, b2, sc, sh, nb, lensk, out);
}

// Round 2
// 302.641 us; speedup vs baseline: 4.5188x; 4.5188x over previous
//
#include <hip/hip_runtime.h>
#include <hip/hip_bf16.h>

#define BS 512
#define LL 128
#define DD 512
#define KK 30
#define GG 8
#define EE 2048
#define HH 1024
#define NROWS (BS*KK)   // 15360
#define NG (BS/GG)      // 64

typedef __attribute__((ext_vector_type(8))) short bf16x8;
typedef __attribute__((ext_vector_type(4))) float f32x4;
typedef __attribute__((address_space(1))) const unsigned int gu32;
typedef __attribute__((address_space(3))) unsigned int lu32;

__device__ __forceinline__ unsigned short f2bf(float f){
  unsigned int x = __float_as_uint(f);
  x = (x + 0x7FFFu + ((x >> 16) & 1u)) >> 16;   // round-to-nearest-even
  return (unsigned short)x;
}
__device__ __forceinline__ float bf2f(unsigned short u){
  return __uint_as_float(((unsigned int)u) << 16);
}
__device__ __forceinline__ unsigned fkey(float f){   // monotonic float->uint
  unsigned b = __float_as_uint(f);
  return (b & 0x80000000u) ? ~b : (b | 0x80000000u);
}
__device__ __forceinline__ float fdec(unsigned k){
  unsigned b = (k & 0x80000000u) ? (k & 0x7FFFFFFFu) : ~k;
  return __uint_as_float(b);
}

// ---------------------------------------------------------------------------
// Kernel 1: per-batch eos/argmax, lengths, masked attention row, top-30.
// ---------------------------------------------------------------------------
__global__ __launch_bounds__(128) void k_prep(const float* __restrict__ atten,
                                              const int* __restrict__ text,
                                              int* __restrict__ idx,
                                              int* __restrict__ lensk){
  const int b = blockIdx.x;
  const int t = threadIdx.x;
  __shared__ float v[128];
  __shared__ int   vi[128];
  __shared__ float row[128];
  __shared__ int   s_eos;

  const int tok = text[b*LL + t];

  v[t] = (float)tok; vi[t] = t; __syncthreads();
  for(int s = 64; s > 0; s >>= 1){
    if(t < s){
      if(v[t+s] > v[t] || (v[t+s] == v[t] && vi[t+s] < vi[t])){ v[t] = v[t+s]; vi[t] = vi[t+s]; }
    }
    __syncthreads();
  }
  if(t == 0) s_eos = vi[0];
  __syncthreads();
  const int eos = s_eos;

  v[t] = (tok != 0) ? 1.0f : 0.0f; __syncthreads();
  for(int s = 64; s > 0; s >>= 1){ if(t < s) v[t] += v[t+s]; __syncthreads(); }
  if(t == 0) lensk[b] = (int)fminf(v[0] - 2.0f, (float)KK);

  float r = (t == 0 || t == eos) ? -1.0f : atten[(size_t)b*LL*LL + (size_t)eos*LL + t];
  if(tok == 0) r = 0.0f;
  row[t] = r; __syncthreads();

  for(int k = 0; k < KK; k++){
    v[t] = row[t]; vi[t] = t; __syncthreads();
    for(int s = 64; s > 0; s >>= 1){
      if(t < s){
        if(v[t+s] > v[t] || (v[t+s] == v[t] && vi[t+s] < vi[t])){ v[t] = v[t+s]; vi[t] = vi[t+s]; }
      }
      __syncthreads();
    }
    if(t == 0){ idx[b*KK + k] = vi[0]; row[vi[0]] = -3.0f; }
    __syncthreads();
  }
}

// ---------------------------------------------------------------------------
// Kernel 2: gather + l2norm (bf16 out) + 8 expert dot products.
// ---------------------------------------------------------------------------
__global__ __launch_bounds__(128) void k_gather(const float* __restrict__ features,
                                                const float* __restrict__ dlp_w,
                                                const float* __restrict__ dlp_b,
                                                const int* __restrict__ idx,
                                                unsigned short* __restrict__ nfeats,
                                                float* __restrict__ hval){
  const int r = blockIdx.x;
  const int b = r / KK;
  const int t = threadIdx.x;
  const int l = idx[r];

  const float4 v = ((const float4*)features)[((size_t)b*LL + l)*(DD/4) + t];
  float ss = v.x*v.x + v.y*v.y + v.z*v.z + v.w*v.w;
  float hg[GG];
#pragma unroll
  for(int g = 0; g < GG; g++){
    const float4 w = ((const float4*)dlp_w)[g*(DD/4) + t];
    hg[g] = v.x*w.x + v.y*w.y + v.z*w.z + v.w*w.w;
  }
#pragma unroll
  for(int off = 32; off > 0; off >>= 1){
    ss += __shfl_down(ss, off);
#pragma unroll
    for(int g = 0; g < GG; g++) hg[g] += __shfl_down(hg[g], off);
  }
  __shared__ float red[2][9];
  __shared__ float s_rn;
  const int wave = t >> 6, lane = t & 63;
  if(lane == 0){
    red[wave][0] = ss;
#pragma unroll
    for(int g = 0; g < GG; g++) red[wave][1+g] = hg[g];
  }
  __syncthreads();
  if(t == 0) s_rn = 1.0f / (sqrtf(red[0][0] + red[1][0]) + 1e-8f);
  if(t < GG) hval[(size_t)r*GG + t] = red[0][1+t] + red[1][1+t] + dlp_b[t];
  __syncthreads();
  const float rn = s_rn;
  ushort4 u;
  u.x = f2bf(v.x*rn); u.y = f2bf(v.y*rn); u.z = f2bf(v.z*rn); u.w = f2bf(v.w*rn);
  ((ushort4*)nfeats)[(size_t)r*(DD/4) + t] = u;
}

// ---------------------------------------------------------------------------
// Kernel 3: grouped-expert linear -> nbbf (bf16).
// ---------------------------------------------------------------------------
__global__ __launch_bounds__(256) void k_dlp(const float* __restrict__ hval,
                                             const float* __restrict__ dlp_lw,
                                             const float* __restrict__ dlp_lb,
                                             unsigned short* __restrict__ nbbf){
  const int et = blockIdx.x;
  const int n  = blockIdx.y;
  const int tid = threadIdx.x;
  __shared__ float hs[GG][GG*KK];
  for(int i = tid; i < GG*GG*KK; i += 256){
    const int g = i / (GG*KK), tt = i % (GG*KK);
    const int m = tt / KK, kq = tt % KK;
    hs[g][tt] = hval[(size_t)(((n*GG + m)*KK) + kq)*GG + g];
  }
  __syncthreads();
  const int h = tid >> 7, c = tid & 127;
  const int e = et*128 + c;
  float acc[4] = {0.f, 0.f, 0.f, 0.f};
#pragma unroll 4
  for(int k = 0; k < GG*KK; k++){
    const float w = dlp_lw[(size_t)k*EE + e];
#pragma unroll
    for(int rr = 0; rr < 4; rr++) acc[rr] += hs[h*4 + rr][k] * w;
  }
  const float lb = dlp_lb[e];
#pragma unroll
  for(int rr = 0; rr < 4; rr++)
    nbbf[(size_t)(n*GG + h*4 + rr)*EE + e] = f2bf(acc[rr] + lb);
}

// ---------------------------------------------------------------------------
// Kernel 4: l2-normalize nbbf rows in place (bf16).
// ---------------------------------------------------------------------------
__global__ __launch_bounds__(256) void k_l2nb(unsigned short* __restrict__ nbbf){
  const int b = blockIdx.x, t = threadIdx.x;
  uint4* p = (uint4*)(nbbf + (size_t)b*EE);
  uint4 u = p[t];
  unsigned short* us = (unsigned short*)&u;
  float f[8]; float ss = 0.f;
#pragma unroll
  for(int j = 0; j < 8; j++){ f[j] = bf2f(us[j]); ss += f[j]*f[j]; }
#pragma unroll
  for(int off = 32; off > 0; off >>= 1) ss += __shfl_down(ss, off);
  __shared__ float red[4];
  __shared__ float s_rn;
  if((t & 63) == 0) red[t >> 6] = ss;
  __syncthreads();
  if(t == 0) s_rn = 1.0f / (sqrtf(red[0] + red[1] + red[2] + red[3]) + 1e-8f);
  __syncthreads();
  const float rn = s_rn;
#pragma unroll
  for(int j = 0; j < 8; j++) us[j] = f2bf(f[j]*rn);
  p[t] = u;
}

// ---------------------------------------------------------------------------
// Kernel 5: transpose+convert weights: src[K][N] f32 -> dst[N][K] bf16.
// ---------------------------------------------------------------------------
__global__ __launch_bounds__(256) void k_wcvt(const float* __restrict__ src,
                                              unsigned short* __restrict__ dst,
                                              int Kd, int Nd){
  __shared__ float tile[32][33];
  const int n0 = blockIdx.x*32, k0 = blockIdx.y*32;
  const int r = threadIdx.x >> 3, c4 = (threadIdx.x & 7)*4;
  const float4 v = *(const float4*)(src + (size_t)(k0 + r)*Nd + n0 + c4);
  tile[r][c4+0] = v.x; tile[r][c4+1] = v.y; tile[r][c4+2] = v.z; tile[r][c4+3] = v.w;
  __syncthreads();
  ushort4 u;
  u.x = f2bf(tile[c4+0][r]); u.y = f2bf(tile[c4+1][r]);
  u.z = f2bf(tile[c4+2][r]); u.w = f2bf(tile[c4+3][r]);
  *(ushort4*)(dst + (size_t)(n0 + r)*Kd + k0 + c4) = u;
}

// ---------------------------------------------------------------------------
// Kernel 6: MFMA bf16 GEMM, 128x128 tile, BK=32, 4 waves (2x2), m97-style.
// A: [M][KD] bf16 row-major. Bt: [ND][KD] bf16 (pre-transposed).
// POOL=false: out = A@B + bias -> bf16 obf[M][ND].
// POOL=true : segmented per-batch (30-row) max of A@B -> atomicMax into pkey.
// ---------------------------------------------------------------------------
template<int KD, int ND, bool POOL>
__global__ __launch_bounds__(256) void k_mgemm(const unsigned short* __restrict__ A,
                                               const unsigned short* __restrict__ Bt,
                                               const float* __restrict__ bias,
                                               unsigned short* __restrict__ obf,
                                               const int* __restrict__ lensk,
                                               unsigned* __restrict__ pkey){
  __shared__ short As[128*32];
  __shared__ short Bs[128*32];
  const int tid  = threadIdx.x;
  const int wave = tid >> 6, lane = tid & 63;
  const int wr = wave >> 1, wc = wave & 1;
  const int lrow = lane & 15, kg = lane >> 4;
  const int m0 = blockIdx.y * 128, n0 = blockIdx.x * 128;

  const unsigned short* Ab = A  + (size_t)m0 * KD;
  const unsigned short* Bb = Bt + (size_t)n0 * KD;

  f32x4 acc[4][4] = {};

  for(int k0 = 0; k0 < KD; k0 += 32){
#pragma unroll
    for(int j = 0; j < 2; j++){
      const int i = tid + j*256;
      const int row = i >> 2, kc = i & 3;
      __builtin_amdgcn_global_load_lds((gu32*)(Ab + (size_t)row*KD + k0 + kc*8),
                                       (lu32*)(As + i*8), 16, 0, 0);
    }
#pragma unroll
    for(int j = 0; j < 2; j++){
      const int i = tid + j*256;
      const int row = i >> 2, kc = i & 3;
      __builtin_amdgcn_global_load_lds((gu32*)(Bb + (size_t)row*KD + k0 + kc*8),
                                       (lu32*)(Bs + i*8), 16, 0, 0);
    }
    __syncthreads();   // drains vmcnt before barrier

    bf16x8 af[4], bg[4];
#pragma unroll
    for(int m = 0; m < 4; m++)
      af[m] = *(const bf16x8*)(As + (wr*64 + m*16 + lrow)*32 + kg*8);
#pragma unroll
    for(int n = 0; n < 4; n++)
      bg[n] = *(const bf16x8*)(Bs + (wc*64 + n*16 + lrow)*32 + kg*8);
#pragma unroll
    for(int m = 0; m < 4; m++)
#pragma unroll
      for(int n = 0; n < 4; n++)
        acc[m][n] = __builtin_amdgcn_mfma_f32_16x16x32_bf16(af[m], bg[n], acc[m][n], 0, 0, 0);
    __syncthreads();
  }

  if constexpr (!POOL){
    const int colb = n0 + wc*64 + lrow;
#pragma unroll
    for(int n = 0; n < 4; n++){
      const float bb = bias[colb + n*16];
#pragma unroll
      for(int m = 0; m < 4; m++){
        const int row = m0 + wr*64 + m*16 + kg*4;
#pragma unroll
        for(int r = 0; r < 4; r++)
          obf[(size_t)(row + r)*ND + colb + n*16] = f2bf(acc[m][n][r] + bb);
      }
    }
  } else {
    const int colb = n0 + wc*64 + lrow;
    int cur_b = -1;
    float mx[4];
#pragma unroll
    for(int m = 0; m < 4; m++){
#pragma unroll
      for(int r = 0; r < 4; r++){
        const int row = m0 + wr*64 + m*16 + kg*4 + r;
        const int bt = row / KK;
        const int rr = row - bt*KK;
        if(bt != cur_b){
          if(cur_b >= 0){
#pragma unroll
            for(int n = 0; n < 4; n++)
              atomicMax(&pkey[(size_t)cur_b*ND + colb + n*16], fkey(mx[n]));
          }
          cur_b = bt;
#pragma unroll
          for(int n = 0; n < 4; n++) mx[n] = -INFINITY;
        }
        if(rr < lensk[bt]){
#pragma unroll
          for(int n = 0; n < 4; n++) mx[n] = fmaxf(mx[n], acc[m][n][r]);
        }
      }
    }
#pragma unroll
    for(int n = 0; n < 4; n++)
      atomicMax(&pkey[(size_t)cur_b*ND + colb + n*16], fkey(mx[n]));
  }
}

// ---------------------------------------------------------------------------
// Kernel 7: BN stats (two-stage deterministic).
// ---------------------------------------------------------------------------
__global__ __launch_bounds__(256) void k_bnstat(const unsigned short* __restrict__ x1,
                                                float* __restrict__ psum,
                                                float* __restrict__ psq){
  const int rb = blockIdx.x, tid = threadIdx.x;
  float s[4] = {0,0,0,0}, q[4] = {0,0,0,0};
  for(int r = 0; r < 64; r++){
    const ushort4 u = *(const ushort4*)(x1 + (size_t)(rb*64 + r)*HH + tid*4);
    const float f0 = bf2f(u.x), f1 = bf2f(u.y), f2 = bf2f(u.z), f3 = bf2f(u.w);
    s[0] += f0; q[0] += f0*f0;
    s[1] += f1; q[1] += f1*f1;
    s[2] += f2; q[2] += f2*f2;
    s[3] += f3; q[3] += f3*f3;
  }
#pragma unroll
  for(int j = 0; j < 4; j++){
    psum[(size_t)rb*HH + tid*4 + j] = s[j];
    psq [(size_t)rb*HH + tid*4 + j] = q[j];
  }
}

__global__ __launch_bounds__(256) void k_bnfin(const float* __restrict__ psum,
                                               const float* __restrict__ psq,
                                               const float* __restrict__ bn_g,
                                               const float* __restrict__ bn_b,
                                               float* __restrict__ sc,
                                               float* __restrict__ sh){
  const int c = blockIdx.x*256 + threadIdx.x;
  float s = 0.f, q = 0.f;
  for(int i = 0; i < 240; i++){ s += psum[(size_t)i*HH + c]; q += psq[(size_t)i*HH + c]; }
  const float mu  = s * (1.0f/NROWS);
  const float var = q * (1.0f/NROWS) - mu*mu;
  const float sv  = bn_g[c] / sqrtf(var + 1e-5f);
  sc[c] = sv;
  sh[c] = bn_b[c] - mu*sv;
}

// ---------------------------------------------------------------------------
// Kernel 8: BN+ReLU applied in place on x1 (bf16).
// ---------------------------------------------------------------------------
__global__ __launch_bounds__(256) void k_bnrelu(unsigned short* __restrict__ x1,
                                                const float* __restrict__ sc,
                                                const float* __restrict__ sh){
  const size_t i = (size_t)blockIdx.x*256 + threadIdx.x;   // chunk of 8 bf16
  const int c0 = (int)((i*8) & (HH-1));
  uint4 u = ((uint4*)x1)[i];
  unsigned short* us = (unsigned short*)&u;
  const float4 s0 = *(const float4*)(sc + c0), s1 = *(const float4*)(sc + c0 + 4);
  const float4 h0 = *(const float4*)(sh + c0), h1 = *(const float4*)(sh + c0 + 4);
  const float scv[8] = {s0.x,s0.y,s0.z,s0.w,s1.x,s1.y,s1.z,s1.w};
  const float shv[8] = {h0.x,h0.y,h0.z,h0.w,h1.x,h1.y,h1.z,h1.w};
#pragma unroll
  for(int j = 0; j < 8; j++)
    us[j] = f2bf(fmaxf(bf2f(us[j])*scv[j] + shv[j], 0.f));
  ((uint4*)x1)[i] = u;
}

// ---------------------------------------------------------------------------
// Kernel 9: init pool keys to key(-inf); Kernel 10: finalize output.
// ---------------------------------------------------------------------------
__global__ __launch_bounds__(256) void k_pinit(unsigned* __restrict__ p){
  const size_t i = (size_t)blockIdx.x*256 + threadIdx.x;
  ((uint4*)p)[i] = make_uint4(0x007FFFFFu, 0x007FFFFFu, 0x007FFFFFu, 0x007FFFFFu);
}

__global__ __launch_bounds__(256) void k_final(const unsigned* __restrict__ pkey,
                                               const float* __restrict__ b2,
                                               const unsigned short* __restrict__ nbbf,
                                               float* __restrict__ out){
  const size_t i = (size_t)blockIdx.x*256 + threadIdx.x;   // per 4 elems
  const int c0 = (int)((i*4) & (EE-1));
  const uint4 k = ((const uint4*)pkey)[i];
  const ushort4 nb4 = ((const ushort4*)nbbf)[i];
  const float4 b = *(const float4*)(b2 + c0);
  float4 o;
  o.x = fdec(k.x) + b.x + bf2f(nb4.x);
  o.y = fdec(k.y) + b.y + bf2f(nb4.y);
  o.z = fdec(k.z) + b.z + bf2f(nb4.z);
  o.w = fdec(k.w) + b.w + bf2f(nb4.w);
  ((float4*)out)[i] = o;
}

// ---------------------------------------------------------------------------
extern "C" void kernel_launch(void* const* d_in, const int* in_sizes, int n_in,
                              void* d_out, int out_size, void* d_ws, size_t ws_size,
                              hipStream_t stream){
  const float* features = (const float*)d_in[0];
  const float* atten    = (const float*)d_in[1];
  const int*   text     = (const int*)  d_in[2];
  const float* dlp_w    = (const float*)d_in[4];
  const float* dlp_b    = (const float*)d_in[5];
  const float* dlp_lw   = (const float*)d_in[6];
  const float* dlp_lb   = (const float*)d_in[7];
  const float* w1       = (const float*)d_in[8];
  const float* b1       = (const float*)d_in[9];
  const float* bn_g     = (const float*)d_in[10];
  const float* bn_b     = (const float*)d_in[11];
  const float* w2       = (const float*)d_in[12];
  const float* b2       = (const float*)d_in[13];
  float* out = (float*)d_out;

  // Workspace layout with lifetime aliasing (total 53,487,616 B):
  //  [0, 4MB): psum | psq | w1t | hval | idx  -- all dead before pkey overlays
  char* ws = (char*)d_ws;
  float*          psum   = (float*)(ws + 0);               //   983,040
  float*          psq    = (float*)(ws + 983040);          //   983,040
  unsigned short* w1t    = (unsigned short*)(ws + 1966080);// 1,048,576
  float*          hval   = (float*)(ws + 3014656);         //   491,520
  int*            idx    = (int*)(ws + 3506176);           //    61,440
  unsigned*       pkey   = (unsigned*)(ws + 0);            // 4,194,304 (overlay)
  int*            lensk  = (int*)(ws + 4194304);           //     2,048
  float*          sc     = (float*)(ws + 4196352);         //     4,096
  float*          sh     = (float*)(ws + 4200448);         //     4,096
  unsigned short* nfeats = (unsigned short*)(ws + 4204544);// 15,728,640
  unsigned short* w2t    = (unsigned short*)(ws + 4204544);// 4,194,304 (overlays nfeats, after gemm1)
  unsigned short* x1     = (unsigned short*)(ws + 19933184);//31,457,280
  unsigned short* nbbf   = (unsigned short*)(ws + 51390464);// 2,097,152

  k_wcvt<<<dim3(HH/32, DD/32), 256, 0, stream>>>(w1, w1t, DD, HH);
  k_prep<<<BS, 128, 0, stream>>>(atten, text, idx, lensk);
  k_gather<<<NROWS, 128, 0, stream>>>(features, dlp_w, dlp_b, idx, nfeats, hval);
  k_dlp<<<dim3(16, NG), 256, 0, stream>>>(hval, dlp_lw, dlp_lb, nbbf);
  k_l2nb<<<BS, 256, 0, stream>>>(nbbf);
  k_mgemm<DD, HH, false><<<dim3(HH/128, NROWS/128), 256, 0, stream>>>(
      nfeats, w1t, b1, x1, nullptr, nullptr);
  k_wcvt<<<dim3(EE/32, HH/32), 256, 0, stream>>>(w2, w2t, HH, EE);   // nfeats now dead
  k_bnstat<<<240, 256, 0, stream>>>(x1, psum, psq);
  k_bnfin<<<4, 256, 0, stream>>>(psum, psq, bn_g, bn_b, sc, sh);
  k_bnrelu<<<(NROWS*HH/8)/256, 256, 0, stream>>>(x1, sc, sh);
  k_pinit<<<(BS*EE/4)/256, 256, 0, stream>>>(pkey);                   // overlays dead region
  k_mgemm<HH, EE, true><<<dim3(EE/128, NROWS/128), 256, 0, stream>>>(
      x1, w2t, nullptr, nullptr, lensk, pkey);
  k_final<<<(BS*EE/4)/256, 256, 0, stream>>>(pkey, b2, nbbf, out);
}

// Round 3
// 269.371 us; speedup vs baseline: 5.0769x; 1.1235x over previous
//
#include <hip/hip_runtime.h>
#include <hip/hip_bf16.h>

#define BS 512
#define LL 128
#define DD 512
#define KK 30
#define GG 8
#define EE 2048
#define HH 1024
#define NROWS (BS*KK)   // 15360
#define NG (BS/GG)      // 64

typedef __attribute__((ext_vector_type(8))) short bf16x8;
typedef __attribute__((ext_vector_type(4))) float f32x4;
typedef __attribute__((address_space(1))) const unsigned int gu32;
typedef __attribute__((address_space(3))) unsigned int lu32;

__device__ __forceinline__ unsigned short f2bf(float f){
  unsigned int x = __float_as_uint(f);
  x = (x + 0x7FFFu + ((x >> 16) & 1u)) >> 16;   // round-to-nearest-even
  return (unsigned short)x;
}
__device__ __forceinline__ float bf2f(unsigned short u){
  return __uint_as_float(((unsigned int)u) << 16);
}
__device__ __forceinline__ unsigned fkey(float f){   // monotonic float->uint
  unsigned b = __float_as_uint(f);
  return (b & 0x80000000u) ? ~b : (b | 0x80000000u);
}
__device__ __forceinline__ float fdec(unsigned k){
  unsigned b = (k & 0x80000000u) ? (k & 0x7FFFFFFFu) : ~k;
  return __uint_as_float(b);
}

// ---------------------------------------------------------------------------
// Kernel 1: per-batch eos/argmax, lengths, masked row, top-30 — single wave,
// shuffle-only (no barriers). Tie rule everywhere: larger value, smaller idx.
// ---------------------------------------------------------------------------
__global__ __launch_bounds__(64) void k_prep(const float* __restrict__ atten,
                                             const int* __restrict__ text,
                                             int* __restrict__ idx,
                                             int* __restrict__ lensk){
  const int b = blockIdx.x;
  const int lane = threadIdx.x;
  const int t0 = text[b*LL + lane];
  const int t1 = text[b*LL + 64 + lane];

  // eos = argmax(text row), first occurrence of max
  int v, vi;
  if(t1 > t0){ v = t1; vi = lane + 64; } else { v = t0; vi = lane; }
#pragma unroll
  for(int off = 32; off; off >>= 1){
    const int ov = __shfl_xor(v, off), oi = __shfl_xor(vi, off);
    if(ov > v || (ov == v && oi < vi)){ v = ov; vi = oi; }
  }
  const int eos = vi;

  const unsigned long long mb0 = __ballot(t0 != 0), mb1 = __ballot(t1 != 0);
  if(lane == 0) lensk[b] = min(__popcll(mb0) + __popcll(mb1) - 2, KK);

  const float a0 = atten[(size_t)b*LL*LL + (size_t)eos*LL + lane];
  const float a1 = atten[(size_t)b*LL*LL + (size_t)eos*LL + 64 + lane];
  float r0 = (t0 == 0) ? 0.f : ((lane == 0 || lane == eos) ? -1.f : a0);
  float r1 = (t1 == 0) ? 0.f : ((lane + 64 == eos) ? -1.f : a1);

  for(int k = 0; k < KK; k++){
    float mv; int mi;
    if(r1 > r0){ mv = r1; mi = lane + 64; } else { mv = r0; mi = lane; }
#pragma unroll
    for(int off = 32; off; off >>= 1){
      const float ov = __shfl_xor(mv, off); const int oi = __shfl_xor(mi, off);
      if(ov > mv || (ov == mv && oi < mi)){ mv = ov; mi = oi; }
    }
    if(lane == 0) idx[b*KK + k] = mi;
    if(mi == lane)      r0 = -3.f;
    if(mi == lane + 64) r1 = -3.f;
  }
}

// ---------------------------------------------------------------------------
// Kernel 2: gather + l2norm (bf16 out) + 8 expert dot products.
// ---------------------------------------------------------------------------
__global__ __launch_bounds__(128) void k_gather(const float* __restrict__ features,
                                                const float* __restrict__ dlp_w,
                                                const float* __restrict__ dlp_b,
                                                const int* __restrict__ idx,
                                                unsigned short* __restrict__ nfeats,
                                                float* __restrict__ hval){
  const int r = blockIdx.x;
  const int b = r / KK;
  const int t = threadIdx.x;
  const int l = idx[r];

  const float4 v = ((const float4*)features)[((size_t)b*LL + l)*(DD/4) + t];
  float ss = v.x*v.x + v.y*v.y + v.z*v.z + v.w*v.w;
  float hg[GG];
#pragma unroll
  for(int g = 0; g < GG; g++){
    const float4 w = ((const float4*)dlp_w)[g*(DD/4) + t];
    hg[g] = v.x*w.x + v.y*w.y + v.z*w.z + v.w*w.w;
  }
#pragma unroll
  for(int off = 32; off > 0; off >>= 1){
    ss += __shfl_down(ss, off);
#pragma unroll
    for(int g = 0; g < GG; g++) hg[g] += __shfl_down(hg[g], off);
  }
  __shared__ float red[2][9];
  __shared__ float s_rn;
  const int wave = t >> 6, lane = t & 63;
  if(lane == 0){
    red[wave][0] = ss;
#pragma unroll
    for(int g = 0; g < GG; g++) red[wave][1+g] = hg[g];
  }
  __syncthreads();
  if(t == 0) s_rn = 1.0f / (sqrtf(red[0][0] + red[1][0]) + 1e-8f);
  if(t < GG) hval[(size_t)r*GG + t] = red[0][1+t] + red[1][1+t] + dlp_b[t];
  __syncthreads();
  const float rn = s_rn;
  ushort4 u;
  u.x = f2bf(v.x*rn); u.y = f2bf(v.y*rn); u.z = f2bf(v.z*rn); u.w = f2bf(v.w*rn);
  ((ushort4*)nfeats)[(size_t)r*(DD/4) + t] = u;
}

// ---------------------------------------------------------------------------
// Kernel 3: grouped-expert linear -> nbbf (bf16).
// ---------------------------------------------------------------------------
__global__ __launch_bounds__(256) void k_dlp(const float* __restrict__ hval,
                                             const float* __restrict__ dlp_lw,
                                             const float* __restrict__ dlp_lb,
                                             unsigned short* __restrict__ nbbf){
  const int et = blockIdx.x;
  const int n  = blockIdx.y;
  const int tid = threadIdx.x;
  __shared__ float hs[GG][GG*KK];
  for(int i = tid; i < GG*GG*KK; i += 256){
    const int g = i / (GG*KK), tt = i % (GG*KK);
    const int m = tt / KK, kq = tt % KK;
    hs[g][tt] = hval[(size_t)(((n*GG + m)*KK) + kq)*GG + g];
  }
  __syncthreads();
  const int h = tid >> 7, c = tid & 127;
  const int e = et*128 + c;
  float acc[4] = {0.f, 0.f, 0.f, 0.f};
#pragma unroll 4
  for(int k = 0; k < GG*KK; k++){
    const float w = dlp_lw[(size_t)k*EE + e];
#pragma unroll
    for(int rr = 0; rr < 4; rr++) acc[rr] += hs[h*4 + rr][k] * w;
  }
  const float lb = dlp_lb[e];
#pragma unroll
  for(int rr = 0; rr < 4; rr++)
    nbbf[(size_t)(n*GG + h*4 + rr)*EE + e] = f2bf(acc[rr] + lb);
}

// ---------------------------------------------------------------------------
// Kernel 4: l2-normalize nbbf rows in place (bf16).
// ---------------------------------------------------------------------------
__global__ __launch_bounds__(256) void k_l2nb(unsigned short* __restrict__ nbbf){
  const int b = blockIdx.x, t = threadIdx.x;
  uint4* p = (uint4*)(nbbf + (size_t)b*EE);
  uint4 u = p[t];
  unsigned short* us = (unsigned short*)&u;
  float f[8]; float ss = 0.f;
#pragma unroll
  for(int j = 0; j < 8; j++){ f[j] = bf2f(us[j]); ss += f[j]*f[j]; }
#pragma unroll
  for(int off = 32; off > 0; off >>= 1) ss += __shfl_down(ss, off);
  __shared__ float red[4];
  __shared__ float s_rn;
  if((t & 63) == 0) red[t >> 6] = ss;
  __syncthreads();
  if(t == 0) s_rn = 1.0f / (sqrtf(red[0] + red[1] + red[2] + red[3]) + 1e-8f);
  __syncthreads();
  const float rn = s_rn;
#pragma unroll
  for(int j = 0; j < 8; j++) us[j] = f2bf(f[j]*rn);
  p[t] = u;
}

// ---------------------------------------------------------------------------
// Kernel 5: transpose+convert weights: src[K][N] f32 -> dst[N][K] bf16.
// ---------------------------------------------------------------------------
__global__ __launch_bounds__(256) void k_wcvt(const float* __restrict__ src,
                                              unsigned short* __restrict__ dst,
                                              int Kd, int Nd){
  __shared__ float tile[32][33];
  const int n0 = blockIdx.x*32, k0 = blockIdx.y*32;
  const int r = threadIdx.x >> 3, c4 = (threadIdx.x & 7)*4;
  const float4 v = *(const float4*)(src + (size_t)(k0 + r)*Nd + n0 + c4);
  tile[r][c4+0] = v.x; tile[r][c4+1] = v.y; tile[r][c4+2] = v.z; tile[r][c4+3] = v.w;
  __syncthreads();
  ushort4 u;
  u.x = f2bf(tile[c4+0][r]); u.y = f2bf(tile[c4+1][r]);
  u.z = f2bf(tile[c4+2][r]); u.w = f2bf(tile[c4+3][r]);
  *(ushort4*)(dst + (size_t)(n0 + r)*Kd + k0 + c4) = u;
}

// ---------------------------------------------------------------------------
// Kernel 6: MFMA bf16 GEMM, 256x256 tile, BK=32, 8 waves (2Mx4N), 3-buffer
// LDS rotation, one raw s_barrier + counted vmcnt per K-tile, XOR granule
// swizzle (pre-swizzled global source, linear gload_lds dest, swizzled read).
// A: [M][KD] bf16 row-major. Bt: [ND][KD] bf16 (pre-transposed).
// POOL=false: out = A@B + bias -> bf16 obf[M][ND].
// POOL=true : segmented per-batch (30-row) max of A@B -> atomicMax into pkey.
// ---------------------------------------------------------------------------
template<int KD, int ND, bool POOL, int NBX>
__global__ __launch_bounds__(512, 2) void k_mgemm(const unsigned short* __restrict__ A,
                                                  const unsigned short* __restrict__ Bt,
                                                  const float* __restrict__ bias,
                                                  unsigned short* __restrict__ obf,
                                                  const int* __restrict__ lensk,
                                                  unsigned* __restrict__ pkey){
  __shared__ short S[3][2][8192];     // 3 bufs x {A,B} x 256rows x 32 bf16 = 96 KiB
  const int tid  = threadIdx.x;
  const int wave = tid >> 6, lane = tid & 63;
  const int wr = wave >> 2, wc = wave & 3;        // 2M x 4N waves
  const int lrow = lane & 15, kg = lane >> 4;

  // bijective XCD-aware swizzle (gridDim.x % 8 == 0 by construction)
  const int nwg = gridDim.x;
  const int cpx = nwg >> 3;
  const int bid = (blockIdx.x & 7) * cpx + (blockIdx.x >> 3);
  const int bx = bid % NBX, by = bid / NBX;
  const int m0 = by * 256, n0 = bx * 256;

  const unsigned short* Ab = A  + (size_t)m0 * KD;
  const unsigned short* Bb = Bt + (size_t)n0 * KD;

#define STAGE(tt, p) { \
  const unsigned short* As_ = Ab + (tt)*32; \
  const unsigned short* Bs_ = Bb + (tt)*32; \
  _Pragma("unroll") \
  for(int c = 0; c < 2; c++){ \
    const int ga = tid + c*512; \
    const int row_ = ga >> 2, sl_ = ga & 3; \
    const int ss_ = sl_ ^ (row_ & 3) ^ ((row_ >> 2) & 3); \
    __builtin_amdgcn_global_load_lds((gu32*)(As_ + (size_t)row_*KD + ss_*8), \
                                     (lu32*)(&S[p][0][ga*8]), 16, 0, 0); \
  } \
  _Pragma("unroll") \
  for(int c = 0; c < 2; c++){ \
    const int ga = tid + c*512; \
    const int row_ = ga >> 2, sl_ = ga & 3; \
    const int ss_ = sl_ ^ (row_ & 3) ^ ((row_ >> 2) & 3); \
    __builtin_amdgcn_global_load_lds((gu32*)(Bs_ + (size_t)row_*KD + ss_*8), \
                                     (lu32*)(&S[p][1][ga*8]), 16, 0, 0); \
  } \
}

  f32x4 acc[8][4] = {};
  const int NT = KD / 32;
  STAGE(0, 0);
  STAGE(1, 1);
  const int sw = kg ^ (lrow & 3) ^ ((lrow >> 2) & 3);   // read-side swizzle slot

  int p = 0;
#pragma unroll 1
  for(int t = 0; t < NT; t++){
    if(t + 1 < NT){ asm volatile("s_waitcnt vmcnt(4)" ::: "memory"); }
    else          { asm volatile("s_waitcnt vmcnt(0)" ::: "memory"); }
    __builtin_amdgcn_s_barrier();
    asm volatile("" ::: "memory");
    if(t + 2 < NT){ int pn = p + 2; if(pn >= 3) pn -= 3; STAGE(t+2, pn); }

    const short* Abuf = &S[p][0][0];
    const short* Bbuf = &S[p][1][0];
    bf16x8 af[8], bg[4];
#pragma unroll
    for(int m = 0; m < 8; m++)
      af[m] = *(const bf16x8*)(Abuf + (wr*128 + m*16 + lrow)*32 + sw*8);
#pragma unroll
    for(int n = 0; n < 4; n++)
      bg[n] = *(const bf16x8*)(Bbuf + (wc*64 + n*16 + lrow)*32 + sw*8);

    __builtin_amdgcn_s_setprio(1);
#pragma unroll
    for(int m = 0; m < 8; m++)
#pragma unroll
      for(int n = 0; n < 4; n++)
        acc[m][n] = __builtin_amdgcn_mfma_f32_16x16x32_bf16(af[m], bg[n], acc[m][n], 0, 0, 0);
    __builtin_amdgcn_s_setprio(0);

    p++; if(p == 3) p = 0;
  }
#undef STAGE

  if constexpr (!POOL){
    const int colb = n0 + wc*64 + lrow;
#pragma unroll
    for(int n = 0; n < 4; n++){
      const float bb = bias[colb + n*16];
#pragma unroll
      for(int m = 0; m < 8; m++){
        const int row = m0 + wr*128 + m*16 + kg*4;
#pragma unroll
        for(int r = 0; r < 4; r++)
          obf[(size_t)(row + r)*ND + colb + n*16] = f2bf(acc[m][n][r] + bb);
      }
    }
  } else {
    const int colb = n0 + wc*64 + lrow;
    int cur_b = -1;
    float mx[4];
#pragma unroll
    for(int m = 0; m < 8; m++){
#pragma unroll
      for(int r = 0; r < 4; r++){
        const int row = m0 + wr*128 + m*16 + kg*4 + r;
        const int bt = row / KK;
        const int rr = row - bt*KK;
        if(bt != cur_b){
          if(cur_b >= 0){
#pragma unroll
            for(int n = 0; n < 4; n++)
              atomicMax(&pkey[(size_t)cur_b*ND + colb + n*16], fkey(mx[n]));
          }
          cur_b = bt;
#pragma unroll
          for(int n = 0; n < 4; n++) mx[n] = -INFINITY;
        }
        if(rr < lensk[bt]){
#pragma unroll
          for(int n = 0; n < 4; n++) mx[n] = fmaxf(mx[n], acc[m][n][r]);
        }
      }
    }
#pragma unroll
    for(int n = 0; n < 4; n++)
      atomicMax(&pkey[(size_t)cur_b*ND + colb + n*16], fkey(mx[n]));
  }
}

// ---------------------------------------------------------------------------
// Kernel 7: BN stats (two-stage deterministic).
// ---------------------------------------------------------------------------
__global__ __launch_bounds__(256) void k_bnstat(const unsigned short* __restrict__ x1,
                                                float* __restrict__ psum,
                                                float* __restrict__ psq){
  const int rb = blockIdx.x, tid = threadIdx.x;
  float s[4] = {0,0,0,0}, q[4] = {0,0,0,0};
  for(int r = 0; r < 64; r++){
    const ushort4 u = *(const ushort4*)(x1 + (size_t)(rb*64 + r)*HH + tid*4);
    const float f0 = bf2f(u.x), f1 = bf2f(u.y), f2 = bf2f(u.z), f3 = bf2f(u.w);
    s[0] += f0; q[0] += f0*f0;
    s[1] += f1; q[1] += f1*f1;
    s[2] += f2; q[2] += f2*f2;
    s[3] += f3; q[3] += f3*f3;
  }
#pragma unroll
  for(int j = 0; j < 4; j++){
    psum[(size_t)rb*HH + tid*4 + j] = s[j];
    psq [(size_t)rb*HH + tid*4 + j] = q[j];
  }
}

__global__ __launch_bounds__(256) void k_bnfin(const float* __restrict__ psum,
                                               const float* __restrict__ psq,
                                               const float* __restrict__ bn_g,
                                               const float* __restrict__ bn_b,
                                               float* __restrict__ sc,
                                               float* __restrict__ sh){
  const int c = blockIdx.x*256 + threadIdx.x;
  float s = 0.f, q = 0.f;
  for(int i = 0; i < 240; i++){ s += psum[(size_t)i*HH + c]; q += psq[(size_t)i*HH + c]; }
  const float mu  = s * (1.0f/NROWS);
  const float var = q * (1.0f/NROWS) - mu*mu;
  const float sv  = bn_g[c] / sqrtf(var + 1e-5f);
  sc[c] = sv;
  sh[c] = bn_b[c] - mu*sv;
}

// ---------------------------------------------------------------------------
// Kernel 8: BN+ReLU applied in place on x1 (bf16).
// ---------------------------------------------------------------------------
__global__ __launch_bounds__(256) void k_bnrelu(unsigned short* __restrict__ x1,
                                                const float* __restrict__ sc,
                                                const float* __restrict__ sh){
  const size_t i = (size_t)blockIdx.x*256 + threadIdx.x;   // chunk of 8 bf16
  const int c0 = (int)((i*8) & (HH-1));
  uint4 u = ((uint4*)x1)[i];
  unsigned short* us = (unsigned short*)&u;
  const float4 s0 = *(const float4*)(sc + c0), s1 = *(const float4*)(sc + c0 + 4);
  const float4 h0 = *(const float4*)(sh + c0), h1 = *(const float4*)(sh + c0 + 4);
  const float scv[8] = {s0.x,s0.y,s0.z,s0.w,s1.x,s1.y,s1.z,s1.w};
  const float shv[8] = {h0.x,h0.y,h0.z,h0.w,h1.x,h1.y,h1.z,h1.w};
#pragma unroll
  for(int j = 0; j < 8; j++)
    us[j] = f2bf(fmaxf(bf2f(us[j])*scv[j] + shv[j], 0.f));
  ((uint4*)x1)[i] = u;
}

// ---------------------------------------------------------------------------
// Kernel 9: init pool keys to key(-inf); Kernel 10: finalize output.
// ---------------------------------------------------------------------------
__global__ __launch_bounds__(256) void k_pinit(unsigned* __restrict__ p){
  const size_t i = (size_t)blockIdx.x*256 + threadIdx.x;
  ((uint4*)p)[i] = make_uint4(0x007FFFFFu, 0x007FFFFFu, 0x007FFFFFu, 0x007FFFFFu);
}

__global__ __launch_bounds__(256) void k_final(const unsigned* __restrict__ pkey,
                                               const float* __restrict__ b2,
                                               const unsigned short* __restrict__ nbbf,
                                               float* __restrict__ out){
  const size_t i = (size_t)blockIdx.x*256 + threadIdx.x;   // per 4 elems
  const int c0 = (int)((i*4) & (EE-1));
  const uint4 k = ((const uint4*)pkey)[i];
  const ushort4 nb4 = ((const ushort4*)nbbf)[i];
  const float4 b = *(const float4*)(b2 + c0);
  float4 o;
  o.x = fdec(k.x) + b.x + bf2f(nb4.x);
  o.y = fdec(k.y) + b.y + bf2f(nb4.y);
  o.z = fdec(k.z) + b.z + bf2f(nb4.z);
  o.w = fdec(k.w) + b.w + bf2f(nb4.w);
  ((float4*)out)[i] = o;
}

// ---------------------------------------------------------------------------
extern "C" void kernel_launch(void* const* d_in, const int* in_sizes, int n_in,
                              void* d_out, int out_size, void* d_ws, size_t ws_size,
                              hipStream_t stream){
  const float* features = (const float*)d_in[0];
  const float* atten    = (const float*)d_in[1];
  const int*   text     = (const int*)  d_in[2];
  const float* dlp_w    = (const float*)d_in[4];
  const float* dlp_b    = (const float*)d_in[5];
  const float* dlp_lw   = (const float*)d_in[6];
  const float* dlp_lb   = (const float*)d_in[7];
  const float* w1       = (const float*)d_in[8];
  const float* b1       = (const float*)d_in[9];
  const float* bn_g     = (const float*)d_in[10];
  const float* bn_b     = (const float*)d_in[11];
  const float* w2       = (const float*)d_in[12];
  const float* b2       = (const float*)d_in[13];
  float* out = (float*)d_out;

  // Workspace layout with lifetime aliasing (total 53,487,616 B):
  char* ws = (char*)d_ws;
  float*          psum   = (float*)(ws + 0);               //   983,040
  float*          psq    = (float*)(ws + 983040);          //   983,040
  unsigned short* w1t    = (unsigned short*)(ws + 1966080);// 1,048,576
  float*          hval   = (float*)(ws + 3014656);         //   491,520
  int*            idx    = (int*)(ws + 3506176);           //    61,440
  unsigned*       pkey   = (unsigned*)(ws + 0);            // 4,194,304 (overlay)
  int*            lensk  = (int*)(ws + 4194304);           //     2,048
  float*          sc     = (float*)(ws + 4196352);         //     4,096
  float*          sh     = (float*)(ws + 4200448);         //     4,096
  unsigned short* nfeats = (unsigned short*)(ws + 4204544);// 15,728,640
  unsigned short* w2t    = (unsigned short*)(ws + 4204544);// 4,194,304 (overlays nfeats, after gemm1)
  unsigned short* x1     = (unsigned short*)(ws + 19933184);//31,457,280
  unsigned short* nbbf   = (unsigned short*)(ws + 51390464);// 2,097,152

  k_wcvt<<<dim3(HH/32, DD/32), 256, 0, stream>>>(w1, w1t, DD, HH);
  k_prep<<<BS, 64, 0, stream>>>(atten, text, idx, lensk);
  k_gather<<<NROWS, 128, 0, stream>>>(features, dlp_w, dlp_b, idx, nfeats, hval);
  k_dlp<<<dim3(16, NG), 256, 0, stream>>>(hval, dlp_lw, dlp_lb, nbbf);
  k_l2nb<<<BS, 256, 0, stream>>>(nbbf);
  k_mgemm<DD, HH, false, HH/256><<<(HH/256)*(NROWS/256), 512, 0, stream>>>(
      nfeats, w1t, b1, x1, nullptr, nullptr);
  k_wcvt<<<dim3(EE/32, HH/32), 256, 0, stream>>>(w2, w2t, HH, EE);   // nfeats now dead
  k_bnstat<<<240, 256, 0, stream>>>(x1, psum, psq);
  k_bnfin<<<4, 256, 0, stream>>>(psum, psq, bn_g, bn_b, sc, sh);
  k_bnrelu<<<(NROWS*HH/8)/256, 256, 0, stream>>>(x1, sc, sh);
  k_pinit<<<(BS*EE/4)/256, 256, 0, stream>>>(pkey);                   // overlays dead region
  k_mgemm<HH, EE, true, EE/256><<<(EE/256)*(NROWS/256), 512, 0, stream>>>(
      x1, w2t, nullptr, nullptr, lensk, pkey);
  k_final<<<(BS*EE/4)/256, 256, 0, stream>>>(pkey, b2, nbbf, out);
}

// Round 4
// 262.731 us; speedup vs baseline: 5.2052x; 1.0253x over previous
//
#include <hip/hip_runtime.h>
#include <hip/hip_bf16.h>

#define BS 512
#define LL 128
#define DD 512
#define KK 30
#define GG 8
#define EE 2048
#define HH 1024
#define NROWS (BS*KK)   // 15360
#define NG (BS/GG)      // 64

typedef __attribute__((ext_vector_type(8))) short bf16x8;
typedef __attribute__((ext_vector_type(4))) float f32x4;
typedef __attribute__((address_space(1))) const unsigned int gu32;
typedef __attribute__((address_space(3))) unsigned int lu32;

__device__ __forceinline__ unsigned short f2bf(float f){
  unsigned int x = __float_as_uint(f);
  x = (x + 0x7FFFu + ((x >> 16) & 1u)) >> 16;   // round-to-nearest-even
  return (unsigned short)x;
}
__device__ __forceinline__ float bf2f(unsigned short u){
  return __uint_as_float(((unsigned int)u) << 16);
}
__device__ __forceinline__ unsigned fkey(float f){   // monotonic float->uint
  unsigned b = __float_as_uint(f);
  return (b & 0x80000000u) ? ~b : (b | 0x80000000u);
}
__device__ __forceinline__ float fdec(unsigned k){
  unsigned b = (k & 0x80000000u) ? (k & 0x7FFFFFFFu) : ~k;
  return __uint_as_float(b);
}

// ---------------------------------------------------------------------------
// Kernel 1: per-batch eos/argmax, lengths, masked row, top-30 — single wave,
// shuffle-only. Tie rule: larger value, smaller index.
// ---------------------------------------------------------------------------
__global__ __launch_bounds__(64) void k_prep(const float* __restrict__ atten,
                                             const int* __restrict__ text,
                                             int* __restrict__ idx,
                                             int* __restrict__ lensk){
  const int b = blockIdx.x;
  const int lane = threadIdx.x;
  const int t0 = text[b*LL + lane];
  const int t1 = text[b*LL + 64 + lane];

  int v, vi;
  if(t1 > t0){ v = t1; vi = lane + 64; } else { v = t0; vi = lane; }
#pragma unroll
  for(int off = 32; off; off >>= 1){
    const int ov = __shfl_xor(v, off), oi = __shfl_xor(vi, off);
    if(ov > v || (ov == v && oi < vi)){ v = ov; vi = oi; }
  }
  const int eos = vi;

  const unsigned long long mb0 = __ballot(t0 != 0), mb1 = __ballot(t1 != 0);
  if(lane == 0) lensk[b] = min(__popcll(mb0) + __popcll(mb1) - 2, KK);

  const float a0 = atten[(size_t)b*LL*LL + (size_t)eos*LL + lane];
  const float a1 = atten[(size_t)b*LL*LL + (size_t)eos*LL + 64 + lane];
  float r0 = (t0 == 0) ? 0.f : ((lane == 0 || lane == eos) ? -1.f : a0);
  float r1 = (t1 == 0) ? 0.f : ((lane + 64 == eos) ? -1.f : a1);

  for(int k = 0; k < KK; k++){
    float mv; int mi;
    if(r1 > r0){ mv = r1; mi = lane + 64; } else { mv = r0; mi = lane; }
#pragma unroll
    for(int off = 32; off; off >>= 1){
      const float ov = __shfl_xor(mv, off); const int oi = __shfl_xor(mi, off);
      if(ov > mv || (ov == mv && oi < mi)){ mv = ov; mi = oi; }
    }
    if(lane == 0) idx[b*KK + k] = mi;
    if(mi == lane)      r0 = -3.f;
    if(mi == lane + 64) r1 = -3.f;
  }
}

// ---------------------------------------------------------------------------
// Kernel 2: gather + l2norm (bf16 out) + 8 expert dot products.
// ---------------------------------------------------------------------------
__global__ __launch_bounds__(128) void k_gather(const float* __restrict__ features,
                                                const float* __restrict__ dlp_w,
                                                const float* __restrict__ dlp_b,
                                                const int* __restrict__ idx,
                                                unsigned short* __restrict__ nfeats,
                                                float* __restrict__ hval){
  const int r = blockIdx.x;
  const int b = r / KK;
  const int t = threadIdx.x;
  const int l = idx[r];

  const float4 v = ((const float4*)features)[((size_t)b*LL + l)*(DD/4) + t];
  float ss = v.x*v.x + v.y*v.y + v.z*v.z + v.w*v.w;
  float hg[GG];
#pragma unroll
  for(int g = 0; g < GG; g++){
    const float4 w = ((const float4*)dlp_w)[g*(DD/4) + t];
    hg[g] = v.x*w.x + v.y*w.y + v.z*w.z + v.w*w.w;
  }
#pragma unroll
  for(int off = 32; off > 0; off >>= 1){
    ss += __shfl_down(ss, off);
#pragma unroll
    for(int g = 0; g < GG; g++) hg[g] += __shfl_down(hg[g], off);
  }
  __shared__ float red[2][9];
  __shared__ float s_rn;
  const int wave = t >> 6, lane = t & 63;
  if(lane == 0){
    red[wave][0] = ss;
#pragma unroll
    for(int g = 0; g < GG; g++) red[wave][1+g] = hg[g];
  }
  __syncthreads();
  if(t == 0) s_rn = 1.0f / (sqrtf(red[0][0] + red[1][0]) + 1e-8f);
  if(t < GG) hval[(size_t)r*GG + t] = red[0][1+t] + red[1][1+t] + dlp_b[t];
  __syncthreads();
  const float rn = s_rn;
  ushort4 u;
  u.x = f2bf(v.x*rn); u.y = f2bf(v.y*rn); u.z = f2bf(v.z*rn); u.w = f2bf(v.w*rn);
  ((ushort4*)nfeats)[(size_t)r*(DD/4) + t] = u;
}

// ---------------------------------------------------------------------------
// Kernel 3: grouped-expert linear -> nbbf (bf16).
// ---------------------------------------------------------------------------
__global__ __launch_bounds__(256) void k_dlp(const float* __restrict__ hval,
                                             const float* __restrict__ dlp_lw,
                                             const float* __restrict__ dlp_lb,
                                             unsigned short* __restrict__ nbbf){
  const int et = blockIdx.x;
  const int n  = blockIdx.y;
  const int tid = threadIdx.x;
  __shared__ float hs[GG][GG*KK];
  for(int i = tid; i < GG*GG*KK; i += 256){
    const int g = i / (GG*KK), tt = i % (GG*KK);
    const int m = tt / KK, kq = tt % KK;
    hs[g][tt] = hval[(size_t)(((n*GG + m)*KK) + kq)*GG + g];
  }
  __syncthreads();
  const int h = tid >> 7, c = tid & 127;
  const int e = et*128 + c;
  float acc[4] = {0.f, 0.f, 0.f, 0.f};
#pragma unroll 4
  for(int k = 0; k < GG*KK; k++){
    const float w = dlp_lw[(size_t)k*EE + e];
#pragma unroll
    for(int rr = 0; rr < 4; rr++) acc[rr] += hs[h*4 + rr][k] * w;
  }
  const float lb = dlp_lb[e];
#pragma unroll
  for(int rr = 0; rr < 4; rr++)
    nbbf[(size_t)(n*GG + h*4 + rr)*EE + e] = f2bf(acc[rr] + lb);
}

// ---------------------------------------------------------------------------
// Kernel 4: l2-normalize nbbf rows in place (bf16).
// ---------------------------------------------------------------------------
__global__ __launch_bounds__(256) void k_l2nb(unsigned short* __restrict__ nbbf){
  const int b = blockIdx.x, t = threadIdx.x;
  uint4* p = (uint4*)(nbbf + (size_t)b*EE);
  uint4 u = p[t];
  unsigned short* us = (unsigned short*)&u;
  float f[8]; float ss = 0.f;
#pragma unroll
  for(int j = 0; j < 8; j++){ f[j] = bf2f(us[j]); ss += f[j]*f[j]; }
#pragma unroll
  for(int off = 32; off > 0; off >>= 1) ss += __shfl_down(ss, off);
  __shared__ float red[4];
  __shared__ float s_rn;
  if((t & 63) == 0) red[t >> 6] = ss;
  __syncthreads();
  if(t == 0) s_rn = 1.0f / (sqrtf(red[0] + red[1] + red[2] + red[3]) + 1e-8f);
  __syncthreads();
  const float rn = s_rn;
#pragma unroll
  for(int j = 0; j < 8; j++) us[j] = f2bf(f[j]*rn);
  p[t] = u;
}

// ---------------------------------------------------------------------------
// Kernel 5: weight transpose+convert: src[K][N] f32 -> dst[N][K] bf16.
// ---------------------------------------------------------------------------
__global__ __launch_bounds__(256) void k_wcvt(const float* __restrict__ src,
                                              unsigned short* __restrict__ dst,
                                              int Kd, int Nd){
  __shared__ float tile[32][33];
  const int n0 = blockIdx.x*32, k0 = blockIdx.y*32;
  const int r = threadIdx.x >> 3, c4 = (threadIdx.x & 7)*4;
  const float4 v = *(const float4*)(src + (size_t)(k0 + r)*Nd + n0 + c4);
  tile[r][c4+0] = v.x; tile[r][c4+1] = v.y; tile[r][c4+2] = v.z; tile[r][c4+3] = v.w;
  __syncthreads();
  ushort4 u;
  u.x = f2bf(tile[c4+0][r]); u.y = f2bf(tile[c4+1][r]);
  u.z = f2bf(tile[c4+2][r]); u.w = f2bf(tile[c4+3][r]);
  *(ushort4*)(dst + (size_t)(n0 + r)*Kd + k0 + c4) = u;
}

// ---------------------------------------------------------------------------
// Kernel 6: MFMA bf16 GEMM, 256x256 tile, BK=64, 8 waves (2Mx4N), double-
// buffered 128KiB LDS, counted vmcnt(8) (a full K-tile compute in flight),
// row-XOR granule swizzle (G4): LDS[row][g] holds global granule g^(row&7);
// reads use the same involution -> every 16-lane quarter covers all 8
// four-bank groups exactly 2x (free). Two s_barriers per K-tile-64.
// ---------------------------------------------------------------------------
template<int KD, int ND, bool POOL, int NBX>
__global__ __launch_bounds__(512, 2) void k_mgemm(const unsigned short* __restrict__ A,
                                                  const unsigned short* __restrict__ Bt,
                                                  const float* __restrict__ bias,
                                                  unsigned short* __restrict__ obf,
                                                  const int* __restrict__ lensk,
                                                  unsigned* __restrict__ pkey){
  __shared__ short S[2][2][256*64];   // [buf][A|B][row*64+col] = 128 KiB
  const int tid  = threadIdx.x;
  const int wave = tid >> 6, lane = tid & 63;
  const int wr = wave >> 2, wc = wave & 3;        // 2M x 4N waves
  const int lrow = lane & 15, kg = lane >> 4;

  const int nwg = gridDim.x, cpx = nwg >> 3;      // grid % 8 == 0
  const int bid = (blockIdx.x & 7)*cpx + (blockIdx.x >> 3);
  const int bx = bid % NBX, by = bid / NBX;
  const int m0 = by*256, n0 = bx*256;

  const unsigned short* Ab = A  + (size_t)m0*KD;
  const unsigned short* Bb = Bt + (size_t)n0*KD;

#define STAGE(tt, p) { \
  _Pragma("unroll") \
  for(int c = 0; c < 4; c++){ \
    const int i_ = tid + c*512; const int r_ = i_ >> 3; \
    const int g_ = (i_ & 7) ^ (r_ & 7); \
    __builtin_amdgcn_global_load_lds((gu32*)(Ab + (size_t)r_*KD + (tt)*64 + g_*8), \
                                     (lu32*)(&S[p][0][i_*8]), 16, 0, 0); \
  } \
  _Pragma("unroll") \
  for(int c = 0; c < 4; c++){ \
    const int i_ = tid + c*512; const int r_ = i_ >> 3; \
    const int g_ = (i_ & 7) ^ (r_ & 7); \
    __builtin_amdgcn_global_load_lds((gu32*)(Bb + (size_t)r_*KD + (tt)*64 + g_*8), \
                                     (lu32*)(&S[p][1][i_*8]), 16, 0, 0); \
  } \
}

  f32x4 acc[8][4] = {};
  const int NT = KD/64;
  STAGE(0, 0);
  STAGE(1, 1);

  const int arow = wr*128 + lrow;     // + m*16
  const int brow = wc*64  + lrow;     // + n*16  (16|stride => row&7 == lrow&7)

  for(int t = 0; t < NT; t++){
    const int p = t & 1;
    if(t + 1 < NT) asm volatile("s_waitcnt vmcnt(8)" ::: "memory");
    else           asm volatile("s_waitcnt vmcnt(0)" ::: "memory");
    __builtin_amdgcn_s_barrier();
    asm volatile("" ::: "memory");

    const short* Abuf = &S[p][0][0];
    const short* Bbuf = &S[p][1][0];
#pragma unroll
    for(int kk = 0; kk < 2; kk++){
      const int gx = ((kk*4 + kg) ^ (lrow & 7))*8;   // swizzled granule offset
      bf16x8 bg[4];
#pragma unroll
      for(int n = 0; n < 4; n++)
        bg[n] = *(const bf16x8*)(Bbuf + (brow + n*16)*64 + gx);
      __builtin_amdgcn_s_setprio(1);
#pragma unroll
      for(int m = 0; m < 8; m++){
        const bf16x8 af = *(const bf16x8*)(Abuf + (arow + m*16)*64 + gx);
#pragma unroll
        for(int n = 0; n < 4; n++)
          acc[m][n] = __builtin_amdgcn_mfma_f32_16x16x32_bf16(af, bg[n], acc[m][n], 0, 0, 0);
      }
      __builtin_amdgcn_s_setprio(0);
    }
    asm volatile("" ::: "memory");
    __builtin_amdgcn_s_barrier();     // all waves done reading buf p
    if(t + 2 < NT){ STAGE(t+2, p); }  // restage just-consumed buffer
  }
#undef STAGE

  if constexpr (!POOL){
    const int colb = n0 + wc*64 + lrow;
#pragma unroll
    for(int n = 0; n < 4; n++){
      const float bb = bias[colb + n*16];
#pragma unroll
      for(int m = 0; m < 8; m++){
        const int row = m0 + wr*128 + m*16 + kg*4;
#pragma unroll
        for(int r = 0; r < 4; r++)
          obf[(size_t)(row + r)*ND + colb + n*16] = f2bf(acc[m][n][r] + bb);
      }
    }
  } else {
    const int colb = n0 + wc*64 + lrow;
    int cur_b = -1;
    float mx[4];
#pragma unroll
    for(int m = 0; m < 8; m++){
#pragma unroll
      for(int r = 0; r < 4; r++){
        const int row = m0 + wr*128 + m*16 + kg*4 + r;
        const int bt = row / KK;
        const int rr = row - bt*KK;
        if(bt != cur_b){
          if(cur_b >= 0){
#pragma unroll
            for(int n = 0; n < 4; n++)
              atomicMax(&pkey[(size_t)cur_b*ND + colb + n*16], fkey(mx[n]));
          }
          cur_b = bt;
#pragma unroll
          for(int n = 0; n < 4; n++) mx[n] = -INFINITY;
        }
        if(rr < lensk[bt]){
#pragma unroll
          for(int n = 0; n < 4; n++) mx[n] = fmaxf(mx[n], acc[m][n][r]);
        }
      }
    }
#pragma unroll
    for(int n = 0; n < 4; n++)
      atomicMax(&pkey[(size_t)cur_b*ND + colb + n*16], fkey(mx[n]));
  }
}

// ---------------------------------------------------------------------------
// Kernel 7: BN stats (two-stage deterministic) + finalize.
// ---------------------------------------------------------------------------
__global__ __launch_bounds__(256) void k_bnstat(const unsigned short* __restrict__ x1,
                                                float* __restrict__ psum,
                                                float* __restrict__ psq){
  const int rb = blockIdx.x, tid = threadIdx.x;
  float s[4] = {0,0,0,0}, q[4] = {0,0,0,0};
  for(int r = 0; r < 64; r++){
    const ushort4 u = *(const ushort4*)(x1 + (size_t)(rb*64 + r)*HH + tid*4);
    const float f0 = bf2f(u.x), f1 = bf2f(u.y), f2 = bf2f(u.z), f3 = bf2f(u.w);
    s[0] += f0; q[0] += f0*f0;
    s[1] += f1; q[1] += f1*f1;
    s[2] += f2; q[2] += f2*f2;
    s[3] += f3; q[3] += f3*f3;
  }
#pragma unroll
  for(int j = 0; j < 4; j++){
    psum[(size_t)rb*HH + tid*4 + j] = s[j];
    psq [(size_t)rb*HH + tid*4 + j] = q[j];
  }
}

__global__ __launch_bounds__(256) void k_bnfin(const float* __restrict__ psum,
                                               const float* __restrict__ psq,
                                               const float* __restrict__ bn_g,
                                               const float* __restrict__ bn_b,
                                               float* __restrict__ sc,
                                               float* __restrict__ sh){
  const int c = blockIdx.x*256 + threadIdx.x;
  float s = 0.f, q = 0.f;
  for(int i = 0; i < 240; i++){ s += psum[(size_t)i*HH + c]; q += psq[(size_t)i*HH + c]; }
  const float mu  = s * (1.0f/NROWS);
  const float var = q * (1.0f/NROWS) - mu*mu;
  const float sv  = bn_g[c] / sqrtf(var + 1e-5f);
  sc[c] = sv;
  sh[c] = bn_b[c] - mu*sv;
}

// ---------------------------------------------------------------------------
// Kernel 8: BN+ReLU in place on x1 (bf16) + pkey init (overlay region
// psum/psq/w1t/hval/idx is dead by now; lensk lies outside the overlay).
// ---------------------------------------------------------------------------
__global__ __launch_bounds__(256) void k_bnrelu(unsigned short* __restrict__ x1,
                                                const float* __restrict__ sc,
                                                const float* __restrict__ sh,
                                                unsigned* __restrict__ pkey){
  const size_t i = (size_t)blockIdx.x*256 + threadIdx.x;   // chunk of 8 bf16
  const int c0 = (int)((i*8) & (HH-1));
  uint4 u = ((uint4*)x1)[i];
  unsigned short* us = (unsigned short*)&u;
  const float4 s0 = *(const float4*)(sc + c0), s1 = *(const float4*)(sc + c0 + 4);
  const float4 h0 = *(const float4*)(sh + c0), h1 = *(const float4*)(sh + c0 + 4);
  const float scv[8] = {s0.x,s0.y,s0.z,s0.w,s1.x,s1.y,s1.z,s1.w};
  const float shv[8] = {h0.x,h0.y,h0.z,h0.w,h1.x,h1.y,h1.z,h1.w};
#pragma unroll
  for(int j = 0; j < 8; j++)
    us[j] = f2bf(fmaxf(bf2f(us[j])*scv[j] + shv[j], 0.f));
  ((uint4*)x1)[i] = u;
  if(blockIdx.x < 1024)
    ((uint4*)pkey)[blockIdx.x*256 + threadIdx.x] =
        make_uint4(0x007FFFFFu, 0x007FFFFFu, 0x007FFFFFu, 0x007FFFFFu);  // key(-inf)
}

// ---------------------------------------------------------------------------
// Kernel 9: finalize output.
// ---------------------------------------------------------------------------
__global__ __launch_bounds__(256) void k_final(const unsigned* __restrict__ pkey,
                                               const float* __restrict__ b2,
                                               const unsigned short* __restrict__ nbbf,
                                               float* __restrict__ out){
  const size_t i = (size_t)blockIdx.x*256 + threadIdx.x;   // per 4 elems
  const int c0 = (int)((i*4) & (EE-1));
  const uint4 k = ((const uint4*)pkey)[i];
  const ushort4 nb4 = ((const ushort4*)nbbf)[i];
  const float4 b = *(const float4*)(b2 + c0);
  float4 o;
  o.x = fdec(k.x) + b.x + bf2f(nb4.x);
  o.y = fdec(k.y) + b.y + bf2f(nb4.y);
  o.z = fdec(k.z) + b.z + bf2f(nb4.z);
  o.w = fdec(k.w) + b.w + bf2f(nb4.w);
  ((float4*)out)[i] = o;
}

// ---------------------------------------------------------------------------
extern "C" void kernel_launch(void* const* d_in, const int* in_sizes, int n_in,
                              void* d_out, int out_size, void* d_ws, size_t ws_size,
                              hipStream_t stream){
  const float* features = (const float*)d_in[0];
  const float* atten    = (const float*)d_in[1];
  const int*   text     = (const int*)  d_in[2];
  const float* dlp_w    = (const float*)d_in[4];
  const float* dlp_b    = (const float*)d_in[5];
  const float* dlp_lw   = (const float*)d_in[6];
  const float* dlp_lb   = (const float*)d_in[7];
  const float* w1       = (const float*)d_in[8];
  const float* b1       = (const float*)d_in[9];
  const float* bn_g     = (const float*)d_in[10];
  const float* bn_b     = (const float*)d_in[11];
  const float* w2       = (const float*)d_in[12];
  const float* b2       = (const float*)d_in[13];
  float* out = (float*)d_out;

  // Workspace layout with lifetime aliasing (total 53,487,616 B):
  char* ws = (char*)d_ws;
  float*          psum   = (float*)(ws + 0);               //   983,040
  float*          psq    = (float*)(ws + 983040);          //   983,040
  unsigned short* w1t    = (unsigned short*)(ws + 1966080);// 1,048,576
  float*          hval   = (float*)(ws + 3014656);         //   491,520
  int*            idx    = (int*)(ws + 3506176);           //    61,440
  unsigned*       pkey   = (unsigned*)(ws + 0);            // 4,194,304 (overlay, live from k_bnrelu on)
  int*            lensk  = (int*)(ws + 4194304);           //     2,048
  float*          sc     = (float*)(ws + 4196352);         //     4,096
  float*          sh     = (float*)(ws + 4200448);         //     4,096
  unsigned short* nfeats = (unsigned short*)(ws + 4204544);// 15,728,640
  unsigned short* w2t    = (unsigned short*)(ws + 4204544);// 4,194,304 (overlays nfeats after gemm1)
  unsigned short* x1     = (unsigned short*)(ws + 19933184);//31,457,280
  unsigned short* nbbf   = (unsigned short*)(ws + 51390464);// 2,097,152

  k_wcvt<<<dim3(HH/32, DD/32), 256, 0, stream>>>(w1, w1t, DD, HH);
  k_prep<<<BS, 64, 0, stream>>>(atten, text, idx, lensk);
  k_gather<<<NROWS, 128, 0, stream>>>(features, dlp_w, dlp_b, idx, nfeats, hval);
  k_dlp<<<dim3(16, NG), 256, 0, stream>>>(hval, dlp_lw, dlp_lb, nbbf);
  k_l2nb<<<BS, 256, 0, stream>>>(nbbf);
  k_mgemm<DD, HH, false, HH/256><<<(HH/256)*(NROWS/256), 512, 0, stream>>>(
      nfeats, w1t, b1, x1, nullptr, nullptr);
  k_wcvt<<<dim3(EE/32, HH/32), 256, 0, stream>>>(w2, w2t, HH, EE);   // nfeats dead now
  k_bnstat<<<240, 256, 0, stream>>>(x1, psum, psq);
  k_bnfin<<<4, 256, 0, stream>>>(psum, psq, bn_g, bn_b, sc, sh);
  k_bnrelu<<<(NROWS*HH/8)/256, 256, 0, stream>>>(x1, sc, sh, pkey);
  k_mgemm<HH, EE, true, EE/256><<<(EE/256)*(NROWS/256), 512, 0, stream>>>(
      x1, w2t, nullptr, nullptr, lensk, pkey);
  k_final<<<(BS*EE/4)/256, 256, 0, stream>>>(pkey, b2, nbbf, out);
}

// Round 5
// 231.039 us; speedup vs baseline: 5.9192x; 1.1372x over previous
//
#include <hip/hip_runtime.h>
#include <hip/hip_bf16.h>

#define BS 512
#define LL 128
#define DD 512
#define KK 30
#define GG 8
#define EE 2048
#define HH 1024
#define NROWS (BS*KK)   // 15360
#define NG (BS/GG)      // 64

typedef __attribute__((ext_vector_type(8))) short bf16x8;
typedef __attribute__((ext_vector_type(4))) float f32x4;
typedef __attribute__((address_space(1))) const unsigned int gu32;
typedef __attribute__((address_space(3))) unsigned int lu32;

__device__ __forceinline__ unsigned short f2bf(float f){
  unsigned int x = __float_as_uint(f);
  x = (x + 0x7FFFu + ((x >> 16) & 1u)) >> 16;   // round-to-nearest-even
  return (unsigned short)x;
}
__device__ __forceinline__ float bf2f(unsigned short u){
  return __uint_as_float(((unsigned int)u) << 16);
}
__device__ __forceinline__ unsigned fkey(float f){   // monotonic float->uint
  unsigned b = __float_as_uint(f);
  return (b & 0x80000000u) ? ~b : (b | 0x80000000u);
}
__device__ __forceinline__ float fdec(unsigned k){
  unsigned b = (k & 0x80000000u) ? (k & 0x7FFFFFFFu) : ~k;
  return __uint_as_float(b);
}

// ---------------------------------------------------------------------------
// Kernel 1: per-batch eos/argmax, lengths, masked row, top-30 — single wave,
// shuffle-only. Tie rule: larger value, smaller index.
// ---------------------------------------------------------------------------
__global__ __launch_bounds__(64) void k_prep(const float* __restrict__ atten,
                                             const int* __restrict__ text,
                                             int* __restrict__ idx,
                                             int* __restrict__ lensk){
  const int b = blockIdx.x;
  const int lane = threadIdx.x;
  const int t0 = text[b*LL + lane];
  const int t1 = text[b*LL + 64 + lane];

  int v, vi;
  if(t1 > t0){ v = t1; vi = lane + 64; } else { v = t0; vi = lane; }
#pragma unroll
  for(int off = 32; off; off >>= 1){
    const int ov = __shfl_xor(v, off), oi = __shfl_xor(vi, off);
    if(ov > v || (ov == v && oi < vi)){ v = ov; vi = oi; }
  }
  const int eos = vi;

  const unsigned long long mb0 = __ballot(t0 != 0), mb1 = __ballot(t1 != 0);
  if(lane == 0) lensk[b] = min(__popcll(mb0) + __popcll(mb1) - 2, KK);

  const float a0 = atten[(size_t)b*LL*LL + (size_t)eos*LL + lane];
  const float a1 = atten[(size_t)b*LL*LL + (size_t)eos*LL + 64 + lane];
  float r0 = (t0 == 0) ? 0.f : ((lane == 0 || lane == eos) ? -1.f : a0);
  float r1 = (t1 == 0) ? 0.f : ((lane + 64 == eos) ? -1.f : a1);

  for(int k = 0; k < KK; k++){
    float mv; int mi;
    if(r1 > r0){ mv = r1; mi = lane + 64; } else { mv = r0; mi = lane; }
#pragma unroll
    for(int off = 32; off; off >>= 1){
      const float ov = __shfl_xor(mv, off); const int oi = __shfl_xor(mi, off);
      if(ov > mv || (ov == mv && oi < mi)){ mv = ov; mi = oi; }
    }
    if(lane == 0) idx[b*KK + k] = mi;
    if(mi == lane)      r0 = -3.f;
    if(mi == lane + 64) r1 = -3.f;
  }
}

// ---------------------------------------------------------------------------
// Kernel 2: gather + l2norm (bf16 out) + 8 expert dot products.
// ---------------------------------------------------------------------------
__global__ __launch_bounds__(128) void k_gather(const float* __restrict__ features,
                                                const float* __restrict__ dlp_w,
                                                const float* __restrict__ dlp_b,
                                                const int* __restrict__ idx,
                                                unsigned short* __restrict__ nfeats,
                                                float* __restrict__ hval){
  const int r = blockIdx.x;
  const int b = r / KK;
  const int t = threadIdx.x;
  const int l = idx[r];

  const float4 v = ((const float4*)features)[((size_t)b*LL + l)*(DD/4) + t];
  float ss = v.x*v.x + v.y*v.y + v.z*v.z + v.w*v.w;
  float hg[GG];
#pragma unroll
  for(int g = 0; g < GG; g++){
    const float4 w = ((const float4*)dlp_w)[g*(DD/4) + t];
    hg[g] = v.x*w.x + v.y*w.y + v.z*w.z + v.w*w.w;
  }
#pragma unroll
  for(int off = 32; off > 0; off >>= 1){
    ss += __shfl_down(ss, off);
#pragma unroll
    for(int g = 0; g < GG; g++) hg[g] += __shfl_down(hg[g], off);
  }
  __shared__ float red[2][9];
  __shared__ float s_rn;
  const int wave = t >> 6, lane = t & 63;
  if(lane == 0){
    red[wave][0] = ss;
#pragma unroll
    for(int g = 0; g < GG; g++) red[wave][1+g] = hg[g];
  }
  __syncthreads();
  if(t == 0) s_rn = 1.0f / (sqrtf(red[0][0] + red[1][0]) + 1e-8f);
  if(t < GG) hval[(size_t)r*GG + t] = red[0][1+t] + red[1][1+t] + dlp_b[t];
  __syncthreads();
  const float rn = s_rn;
  ushort4 u;
  u.x = f2bf(v.x*rn); u.y = f2bf(v.y*rn); u.z = f2bf(v.z*rn); u.w = f2bf(v.w*rn);
  ((ushort4*)nfeats)[(size_t)r*(DD/4) + t] = u;
}

// ---------------------------------------------------------------------------
// Kernel 3: grouped-expert linear -> nbbf (bf16).
// ---------------------------------------------------------------------------
__global__ __launch_bounds__(256) void k_dlp(const float* __restrict__ hval,
                                             const float* __restrict__ dlp_lw,
                                             const float* __restrict__ dlp_lb,
                                             unsigned short* __restrict__ nbbf){
  const int et = blockIdx.x;
  const int n  = blockIdx.y;
  const int tid = threadIdx.x;
  __shared__ float hs[GG][GG*KK];
  for(int i = tid; i < GG*GG*KK; i += 256){
    const int g = i / (GG*KK), tt = i % (GG*KK);
    const int m = tt / KK, kq = tt % KK;
    hs[g][tt] = hval[(size_t)(((n*GG + m)*KK) + kq)*GG + g];
  }
  __syncthreads();
  const int h = tid >> 7, c = tid & 127;
  const int e = et*128 + c;
  float acc[4] = {0.f, 0.f, 0.f, 0.f};
#pragma unroll 4
  for(int k = 0; k < GG*KK; k++){
    const float w = dlp_lw[(size_t)k*EE + e];
#pragma unroll
    for(int rr = 0; rr < 4; rr++) acc[rr] += hs[h*4 + rr][k] * w;
  }
  const float lb = dlp_lb[e];
#pragma unroll
  for(int rr = 0; rr < 4; rr++)
    nbbf[(size_t)(n*GG + h*4 + rr)*EE + e] = f2bf(acc[rr] + lb);
}

// ---------------------------------------------------------------------------
// Kernel 4: l2-normalize nbbf rows in place (bf16).
// ---------------------------------------------------------------------------
__global__ __launch_bounds__(256) void k_l2nb(unsigned short* __restrict__ nbbf){
  const int b = blockIdx.x, t = threadIdx.x;
  uint4* p = (uint4*)(nbbf + (size_t)b*EE);
  uint4 u = p[t];
  unsigned short* us = (unsigned short*)&u;
  float f[8]; float ss = 0.f;
#pragma unroll
  for(int j = 0; j < 8; j++){ f[j] = bf2f(us[j]); ss += f[j]*f[j]; }
#pragma unroll
  for(int off = 32; off > 0; off >>= 1) ss += __shfl_down(ss, off);
  __shared__ float red[4];
  __shared__ float s_rn;
  if((t & 63) == 0) red[t >> 6] = ss;
  __syncthreads();
  if(t == 0) s_rn = 1.0f / (sqrtf(red[0] + red[1] + red[2] + red[3]) + 1e-8f);
  __syncthreads();
  const float rn = s_rn;
#pragma unroll
  for(int j = 0; j < 8; j++) us[j] = f2bf(f[j]*rn);
  p[t] = u;
}

// ---------------------------------------------------------------------------
// Kernel 5: weight transpose+convert: src[K][N] f32 -> dst[N][K] bf16.
// ---------------------------------------------------------------------------
__global__ __launch_bounds__(256) void k_wcvt(const float* __restrict__ src,
                                              unsigned short* __restrict__ dst,
                                              int Kd, int Nd){
  __shared__ float tile[32][33];
  const int n0 = blockIdx.x*32, k0 = blockIdx.y*32;
  const int r = threadIdx.x >> 3, c4 = (threadIdx.x & 7)*4;
  const float4 v = *(const float4*)(src + (size_t)(k0 + r)*Nd + n0 + c4);
  tile[r][c4+0] = v.x; tile[r][c4+1] = v.y; tile[r][c4+2] = v.z; tile[r][c4+3] = v.w;
  __syncthreads();
  ushort4 u;
  u.x = f2bf(tile[c4+0][r]); u.y = f2bf(tile[c4+1][r]);
  u.z = f2bf(tile[c4+2][r]); u.w = f2bf(tile[c4+3][r]);
  *(ushort4*)(dst + (size_t)(n0 + r)*Kd + k0 + c4) = u;
}

// ---------------------------------------------------------------------------
// Kernel 6: MFMA bf16 GEMM, 256x256 tile, BK=64, 8 waves (2Mx4N), double-
// buffered 128KiB LDS, TWO-PHASE K-step with counted per-phase vmcnt:
//   P1: vmcnt(2); bar; issue 6 stage-loads for t+1 (A0,A2,B0..B3 — the
//       chunks phase 1 of t+1 needs first, exploiting in-order vmcnt
//       retirement); ds_read bg[all]+af[m0..3]; 32 MFMA (setprio).
//   P2: vmcnt(6); bar; issue 2 stage-loads (A1,A3); ds_read af[m4..7];
//       32 MFMA (setprio).
// Buffer safety: stages for t+1 are issued after t.P1's barrier, which
// certifies every wave finished its t-1.P2 reads of that buffer.
// Row-XOR granule swizzle as in R4 (measured 0 bank conflicts).
// STATS (GEMM1): per-column sum/sumsq of (acc+bias) reduced via shfl_xor
// over the 4 kg-groups; unique-writer psum[2*by+wr][col] — deterministic.
// POOL (GEMM2): segmented per-batch (30-row) max -> atomicMax on fkey.
// ---------------------------------------------------------------------------
template<int KD, int ND, bool POOL, bool STATS, int NBX>
__global__ __launch_bounds__(512, 2) void k_mgemm(const unsigned short* __restrict__ A,
                                                  const unsigned short* __restrict__ Bt,
                                                  const float* __restrict__ bias,
                                                  unsigned short* __restrict__ obf,
                                                  const int* __restrict__ lensk,
                                                  unsigned* __restrict__ pkey,
                                                  float* __restrict__ psum,
                                                  float* __restrict__ psq){
  __shared__ short S[2][2][256*64];   // [buf][A|B][row*64+col] = 128 KiB
  const int tid  = threadIdx.x;
  const int wave = tid >> 6, lane = tid & 63;
  const int wr = wave >> 2, wc = wave & 3;        // 2M x 4N waves
  const int lrow = lane & 15, kg = lane >> 4;

  const int nwg = gridDim.x, cpx = nwg >> 3;      // grid % 8 == 0
  const int bid = (blockIdx.x & 7)*cpx + (blockIdx.x >> 3);
  const int bx = bid % NBX, by = bid / NBX;
  const int m0 = by*256, n0 = bx*256;

  const unsigned short* Ab = A  + (size_t)m0*KD;
  const unsigned short* Bb = Bt + (size_t)n0*KD;

  // one chunk = 64 rows x 64 k, 1 gload_lds x 16B per thread
#define STG_A(tt, p, c) { \
  const int i_ = tid + (c)*512; const int r_ = i_ >> 3; \
  const int g_ = (i_ & 7) ^ (r_ & 7); \
  __builtin_amdgcn_global_load_lds((gu32*)(Ab + (size_t)r_*KD + (tt)*64 + g_*8), \
                                   (lu32*)(&S[p][0][i_*8]), 16, 0, 0); }
#define STG_B(tt, p, c) { \
  const int i_ = tid + (c)*512; const int r_ = i_ >> 3; \
  const int g_ = (i_ & 7) ^ (r_ & 7); \
  __builtin_amdgcn_global_load_lds((gu32*)(Bb + (size_t)r_*KD + (tt)*64 + g_*8), \
                                   (lu32*)(&S[p][1][i_*8]), 16, 0, 0); }

  f32x4 acc[8][4] = {};
  const int NT = KD/64;

  // prologue: tile 0, in need-first order (A0,A2,B0..B3, then A1,A3)
  STG_A(0, 0, 0) STG_A(0, 0, 2)
  STG_B(0, 0, 0) STG_B(0, 0, 1) STG_B(0, 0, 2) STG_B(0, 0, 3)
  STG_A(0, 0, 1) STG_A(0, 0, 3)

  const int arow = wr*128 + lrow;     // + m*16
  const int brow = wc*64  + lrow;     // + n*16  (16|stride => row&7 == lrow&7)
  const int gx0 = ((0*4 + kg) ^ (lrow & 7))*8;   // swizzled granule, kk=0
  const int gx1 = ((1*4 + kg) ^ (lrow & 7))*8;   // swizzled granule, kk=1

  for(int t = 0; t < NT; t++){
    const int p = t & 1;
    const short* Abuf = &S[p][0][0];
    const short* Bbuf = &S[p][1][0];

    // ---------------- Phase 1 ----------------
    asm volatile("s_waitcnt vmcnt(2)" ::: "memory");   // t's A0,A2,B0..B3 landed
    __builtin_amdgcn_s_barrier();
    asm volatile("" ::: "memory");
    if(t + 1 < NT){
      STG_A(t+1, p^1, 0) STG_A(t+1, p^1, 2)
      STG_B(t+1, p^1, 0) STG_B(t+1, p^1, 1) STG_B(t+1, p^1, 2) STG_B(t+1, p^1, 3)
    }
    bf16x8 bg0[4], bg1[4], af[4];
#pragma unroll
    for(int n = 0; n < 4; n++){
      bg0[n] = *(const bf16x8*)(Bbuf + (brow + n*16)*64 + gx0);
      bg1[n] = *(const bf16x8*)(Bbuf + (brow + n*16)*64 + gx1);
    }
#pragma unroll
    for(int m = 0; m < 4; m++)
      af[m] = *(const bf16x8*)(Abuf + (arow + m*16)*64 + gx0);
    __builtin_amdgcn_s_setprio(1);
#pragma unroll
    for(int m = 0; m < 4; m++)
#pragma unroll
      for(int n = 0; n < 4; n++)
        acc[m][n] = __builtin_amdgcn_mfma_f32_16x16x32_bf16(af[m], bg0[n], acc[m][n], 0, 0, 0);
#pragma unroll
    for(int m = 0; m < 4; m++)
      af[m] = *(const bf16x8*)(Abuf + (arow + m*16)*64 + gx1);
#pragma unroll
    for(int m = 0; m < 4; m++)
#pragma unroll
      for(int n = 0; n < 4; n++)
        acc[m][n] = __builtin_amdgcn_mfma_f32_16x16x32_bf16(af[m], bg1[n], acc[m][n], 0, 0, 0);
    __builtin_amdgcn_s_setprio(0);

    // ---------------- Phase 2 ----------------
    if(t + 1 < NT) asm volatile("s_waitcnt vmcnt(6)" ::: "memory");  // t's A1,A3 landed
    else           asm volatile("s_waitcnt vmcnt(0)" ::: "memory");
    __builtin_amdgcn_s_barrier();
    asm volatile("" ::: "memory");
    if(t + 1 < NT){ STG_A(t+1, p^1, 1) STG_A(t+1, p^1, 3) }
#pragma unroll
    for(int m = 0; m < 4; m++)
      af[m] = *(const bf16x8*)(Abuf + (arow + 64 + m*16)*64 + gx0);
    __builtin_amdgcn_s_setprio(1);
#pragma unroll
    for(int m = 0; m < 4; m++)
#pragma unroll
      for(int n = 0; n < 4; n++)
        acc[4+m][n] = __builtin_amdgcn_mfma_f32_16x16x32_bf16(af[m], bg0[n], acc[4+m][n], 0, 0, 0);
#pragma unroll
    for(int m = 0; m < 4; m++)
      af[m] = *(const bf16x8*)(Abuf + (arow + 64 + m*16)*64 + gx1);
#pragma unroll
    for(int m = 0; m < 4; m++)
#pragma unroll
      for(int n = 0; n < 4; n++)
        acc[4+m][n] = __builtin_amdgcn_mfma_f32_16x16x32_bf16(af[m], bg1[n], acc[4+m][n], 0, 0, 0);
    __builtin_amdgcn_s_setprio(0);
  }
#undef STG_A
#undef STG_B

  if constexpr (!POOL){
    const int colb = n0 + wc*64 + lrow;
#pragma unroll
    for(int n = 0; n < 4; n++){
      const float bb = bias[colb + n*16];
      if constexpr (STATS){
        float sv = 0.f, qv = 0.f;
#pragma unroll
        for(int m = 0; m < 8; m++)
#pragma unroll
          for(int r = 0; r < 4; r++){
            const float v = acc[m][n][r] + bb; sv += v; qv += v*v;
          }
        sv += __shfl_xor(sv, 16); sv += __shfl_xor(sv, 32);
        qv += __shfl_xor(qv, 16); qv += __shfl_xor(qv, 32);
        if(lane < 16){
          psum[(size_t)(by*2 + wr)*ND + colb + n*16] = sv;
          psq [(size_t)(by*2 + wr)*ND + colb + n*16] = qv;
        }
      }
#pragma unroll
      for(int m = 0; m < 8; m++){
        const int row = m0 + wr*128 + m*16 + kg*4;
#pragma unroll
        for(int r = 0; r < 4; r++)
          obf[(size_t)(row + r)*ND + colb + n*16] = f2bf(acc[m][n][r] + bb);
      }
    }
  } else {
    const int colb = n0 + wc*64 + lrow;
    int cur_b = -1;
    float mx[4];
#pragma unroll
    for(int m = 0; m < 8; m++){
#pragma unroll
      for(int r = 0; r < 4; r++){
        const int row = m0 + wr*128 + m*16 + kg*4 + r;
        const int bt = row / KK;
        const int rr = row - bt*KK;
        if(bt != cur_b){
          if(cur_b >= 0){
#pragma unroll
            for(int n = 0; n < 4; n++)
              atomicMax(&pkey[(size_t)cur_b*ND + colb + n*16], fkey(mx[n]));
          }
          cur_b = bt;
#pragma unroll
          for(int n = 0; n < 4; n++) mx[n] = -INFINITY;
        }
        if(rr < lensk[bt]){
#pragma unroll
          for(int n = 0; n < 4; n++) mx[n] = fmaxf(mx[n], acc[m][n][r]);
        }
      }
    }
#pragma unroll
    for(int n = 0; n < 4; n++)
      atomicMax(&pkey[(size_t)cur_b*ND + colb + n*16], fkey(mx[n]));
  }
}

// ---------------------------------------------------------------------------
// Kernel 7: BN finalize from GEMM1's fused partials (120 row-groups).
// ---------------------------------------------------------------------------
__global__ __launch_bounds__(256) void k_bnfin(const float* __restrict__ psum,
                                               const float* __restrict__ psq,
                                               const float* __restrict__ bn_g,
                                               const float* __restrict__ bn_b,
                                               float* __restrict__ sc,
                                               float* __restrict__ sh){
  const int c = blockIdx.x*256 + threadIdx.x;
  float s = 0.f, q = 0.f;
  for(int i = 0; i < 120; i++){ s += psum[(size_t)i*HH + c]; q += psq[(size_t)i*HH + c]; }
  const float mu  = s * (1.0f/NROWS);
  const float var = q * (1.0f/NROWS) - mu*mu;
  const float sv  = bn_g[c] / sqrtf(var + 1e-5f);
  sc[c] = sv;
  sh[c] = bn_b[c] - mu*sv;
}

// ---------------------------------------------------------------------------
// Kernel 8: BN+ReLU in place on x1 (bf16) + pkey init (overlay region
// psum/psq/w1t/hval/idx is dead by now; lensk lies outside the overlay).
// ---------------------------------------------------------------------------
__global__ __launch_bounds__(256) void k_bnrelu(unsigned short* __restrict__ x1,
                                                const float* __restrict__ sc,
                                                const float* __restrict__ sh,
                                                unsigned* __restrict__ pkey){
  const size_t i = (size_t)blockIdx.x*256 + threadIdx.x;   // chunk of 8 bf16
  const int c0 = (int)((i*8) & (HH-1));
  uint4 u = ((uint4*)x1)[i];
  unsigned short* us = (unsigned short*)&u;
  const float4 s0 = *(const float4*)(sc + c0), s1 = *(const float4*)(sc + c0 + 4);
  const float4 h0 = *(const float4*)(sh + c0), h1 = *(const float4*)(sh + c0 + 4);
  const float scv[8] = {s0.x,s0.y,s0.z,s0.w,s1.x,s1.y,s1.z,s1.w};
  const float shv[8] = {h0.x,h0.y,h0.z,h0.w,h1.x,h1.y,h1.z,h1.w};
#pragma unroll
  for(int j = 0; j < 8; j++)
    us[j] = f2bf(fmaxf(bf2f(us[j])*scv[j] + shv[j], 0.f));
  ((uint4*)x1)[i] = u;
  if(blockIdx.x < 1024)
    ((uint4*)pkey)[blockIdx.x*256 + threadIdx.x] =
        make_uint4(0x007FFFFFu, 0x007FFFFFu, 0x007FFFFFu, 0x007FFFFFu);  // key(-inf)
}

// ---------------------------------------------------------------------------
// Kernel 9: finalize output.
// ---------------------------------------------------------------------------
__global__ __launch_bounds__(256) void k_final(const unsigned* __restrict__ pkey,
                                               const float* __restrict__ b2,
                                               const unsigned short* __restrict__ nbbf,
                                               float* __restrict__ out){
  const size_t i = (size_t)blockIdx.x*256 + threadIdx.x;   // per 4 elems
  const int c0 = (int)((i*4) & (EE-1));
  const uint4 k = ((const uint4*)pkey)[i];
  const ushort4 nb4 = ((const ushort4*)nbbf)[i];
  const float4 b = *(const float4*)(b2 + c0);
  float4 o;
  o.x = fdec(k.x) + b.x + bf2f(nb4.x);
  o.y = fdec(k.y) + b.y + bf2f(nb4.y);
  o.z = fdec(k.z) + b.z + bf2f(nb4.z);
  o.w = fdec(k.w) + b.w + bf2f(nb4.w);
  ((float4*)out)[i] = o;
}

// ---------------------------------------------------------------------------
extern "C" void kernel_launch(void* const* d_in, const int* in_sizes, int n_in,
                              void* d_out, int out_size, void* d_ws, size_t ws_size,
                              hipStream_t stream){
  const float* features = (const float*)d_in[0];
  const float* atten    = (const float*)d_in[1];
  const int*   text     = (const int*)  d_in[2];
  const float* dlp_w    = (const float*)d_in[4];
  const float* dlp_b    = (const float*)d_in[5];
  const float* dlp_lw   = (const float*)d_in[6];
  const float* dlp_lb   = (const float*)d_in[7];
  const float* w1       = (const float*)d_in[8];
  const float* b1       = (const float*)d_in[9];
  const float* bn_g     = (const float*)d_in[10];
  const float* bn_b     = (const float*)d_in[11];
  const float* w2       = (const float*)d_in[12];
  const float* b2       = (const float*)d_in[13];
  float* out = (float*)d_out;

  // Workspace layout with lifetime aliasing:
  char* ws = (char*)d_ws;
  float*          psum   = (float*)(ws + 0);               //   491,520 (120x1024)
  float*          psq    = (float*)(ws + 983040);          //   491,520
  unsigned short* w1t    = (unsigned short*)(ws + 1966080);// 1,048,576
  float*          hval   = (float*)(ws + 3014656);         //   491,520
  int*            idx    = (int*)(ws + 3506176);           //    61,440
  unsigned*       pkey   = (unsigned*)(ws + 0);            // 4,194,304 (overlay, live from k_bnrelu on)
  int*            lensk  = (int*)(ws + 4194304);           //     2,048
  float*          sc     = (float*)(ws + 4196352);         //     4,096
  float*          sh     = (float*)(ws + 4200448);         //     4,096
  unsigned short* nfeats = (unsigned short*)(ws + 4204544);// 15,728,640
  unsigned short* w2t    = (unsigned short*)(ws + 4204544);// 4,194,304 (overlays nfeats after gemm1)
  unsigned short* x1     = (unsigned short*)(ws + 19933184);//31,457,280
  unsigned short* nbbf   = (unsigned short*)(ws + 51390464);// 2,097,152

  k_wcvt<<<dim3(HH/32, DD/32), 256, 0, stream>>>(w1, w1t, DD, HH);
  k_prep<<<BS, 64, 0, stream>>>(atten, text, idx, lensk);
  k_gather<<<NROWS, 128, 0, stream>>>(features, dlp_w, dlp_b, idx, nfeats, hval);
  k_dlp<<<dim3(16, NG), 256, 0, stream>>>(hval, dlp_lw, dlp_lb, nbbf);
  k_l2nb<<<BS, 256, 0, stream>>>(nbbf);
  k_mgemm<DD, HH, false, true, HH/256><<<(HH/256)*(NROWS/256), 512, 0, stream>>>(
      nfeats, w1t, b1, x1, nullptr, nullptr, psum, psq);
  k_wcvt<<<dim3(EE/32, HH/32), 256, 0, stream>>>(w2, w2t, HH, EE);   // nfeats dead now
  k_bnfin<<<4, 256, 0, stream>>>(psum, psq, bn_g, bn_b, sc, sh);
  k_bnrelu<<<(NROWS*HH/8)/256, 256, 0, stream>>>(x1, sc, sh, pkey);
  k_mgemm<HH, EE, true, false, EE/256><<<(EE/256)*(NROWS/256), 512, 0, stream>>>(
      x1, w2t, nullptr, nullptr, lensk, pkey, nullptr, nullptr);
  k_final<<<(BS*EE/4)/256, 256, 0, stream>>>(pkey, b2, nbbf, out);
}

// Round 6
// 209.802 us; speedup vs baseline: 6.5184x; 1.1012x over previous
//
#include <hip/hip_runtime.h>
#include <hip/hip_bf16.h>

#define BS 512
#define LL 128
#define DD 512
#define KK 30
#define GG 8
#define EE 2048
#define HH 1024
#define NROWS (BS*KK)   // 15360
#define NG (BS/GG)      // 64

typedef __attribute__((ext_vector_type(8))) short bf16x8;
typedef __attribute__((ext_vector_type(4))) float f32x4;
typedef __attribute__((address_space(1))) const unsigned int gu32;
typedef __attribute__((address_space(3))) unsigned int lu32;

__device__ __forceinline__ unsigned short f2bf(float f){
  unsigned int x = __float_as_uint(f);
  x = (x + 0x7FFFu + ((x >> 16) & 1u)) >> 16;   // round-to-nearest-even
  return (unsigned short)x;
}
__device__ __forceinline__ float bf2f(unsigned short u){
  return __uint_as_float(((unsigned int)u) << 16);
}
__device__ __forceinline__ unsigned fkey(float f){   // monotonic float->uint
  unsigned b = __float_as_uint(f);
  return (b & 0x80000000u) ? ~b : (b | 0x80000000u);
}
__device__ __forceinline__ float fdec(unsigned k){
  unsigned b = (k & 0x80000000u) ? (k & 0x7FFFFFFFu) : ~k;
  return __uint_as_float(b);
}

// ---------------------------------------------------------------------------
// Kernel 1: per-batch eos/argmax, lengths, masked row, top-30 — single wave,
// shuffle-only. Tie rule: larger value, smaller index.
// ---------------------------------------------------------------------------
__global__ __launch_bounds__(64) void k_prep(const float* __restrict__ atten,
                                             const int* __restrict__ text,
                                             int* __restrict__ idx,
                                             int* __restrict__ lensk){
  const int b = blockIdx.x;
  const int lane = threadIdx.x;
  const int t0 = text[b*LL + lane];
  const int t1 = text[b*LL + 64 + lane];

  int v, vi;
  if(t1 > t0){ v = t1; vi = lane + 64; } else { v = t0; vi = lane; }
#pragma unroll
  for(int off = 32; off; off >>= 1){
    const int ov = __shfl_xor(v, off), oi = __shfl_xor(vi, off);
    if(ov > v || (ov == v && oi < vi)){ v = ov; vi = oi; }
  }
  const int eos = vi;

  const unsigned long long mb0 = __ballot(t0 != 0), mb1 = __ballot(t1 != 0);
  if(lane == 0) lensk[b] = min(__popcll(mb0) + __popcll(mb1) - 2, KK);

  const float a0 = atten[(size_t)b*LL*LL + (size_t)eos*LL + lane];
  const float a1 = atten[(size_t)b*LL*LL + (size_t)eos*LL + 64 + lane];
  float r0 = (t0 == 0) ? 0.f : ((lane == 0 || lane == eos) ? -1.f : a0);
  float r1 = (t1 == 0) ? 0.f : ((lane + 64 == eos) ? -1.f : a1);

  for(int k = 0; k < KK; k++){
    float mv; int mi;
    if(r1 > r0){ mv = r1; mi = lane + 64; } else { mv = r0; mi = lane; }
#pragma unroll
    for(int off = 32; off; off >>= 1){
      const float ov = __shfl_xor(mv, off); const int oi = __shfl_xor(mi, off);
      if(ov > mv || (ov == mv && oi < mi)){ mv = ov; mi = oi; }
    }
    if(lane == 0) idx[b*KK + k] = mi;
    if(mi == lane)      r0 = -3.f;
    if(mi == lane + 64) r1 = -3.f;
  }
}

// ---------------------------------------------------------------------------
// Kernel 2: gather + l2norm (bf16 out) + 8 expert dot products.
// ---------------------------------------------------------------------------
__global__ __launch_bounds__(128) void k_gather(const float* __restrict__ features,
                                                const float* __restrict__ dlp_w,
                                                const float* __restrict__ dlp_b,
                                                const int* __restrict__ idx,
                                                unsigned short* __restrict__ nfeats,
                                                float* __restrict__ hval){
  const int r = blockIdx.x;
  const int b = r / KK;
  const int t = threadIdx.x;
  const int l = idx[r];

  const float4 v = ((const float4*)features)[((size_t)b*LL + l)*(DD/4) + t];
  float ss = v.x*v.x + v.y*v.y + v.z*v.z + v.w*v.w;
  float hg[GG];
#pragma unroll
  for(int g = 0; g < GG; g++){
    const float4 w = ((const float4*)dlp_w)[g*(DD/4) + t];
    hg[g] = v.x*w.x + v.y*w.y + v.z*w.z + v.w*w.w;
  }
#pragma unroll
  for(int off = 32; off > 0; off >>= 1){
    ss += __shfl_down(ss, off);
#pragma unroll
    for(int g = 0; g < GG; g++) hg[g] += __shfl_down(hg[g], off);
  }
  __shared__ float red[2][9];
  __shared__ float s_rn;
  const int wave = t >> 6, lane = t & 63;
  if(lane == 0){
    red[wave][0] = ss;
#pragma unroll
    for(int g = 0; g < GG; g++) red[wave][1+g] = hg[g];
  }
  __syncthreads();
  if(t == 0) s_rn = 1.0f / (sqrtf(red[0][0] + red[1][0]) + 1e-8f);
  if(t < GG) hval[(size_t)r*GG + t] = red[0][1+t] + red[1][1+t] + dlp_b[t];
  __syncthreads();
  const float rn = s_rn;
  ushort4 u;
  u.x = f2bf(v.x*rn); u.y = f2bf(v.y*rn); u.z = f2bf(v.z*rn); u.w = f2bf(v.w*rn);
  ((ushort4*)nfeats)[(size_t)r*(DD/4) + t] = u;
}

// ---------------------------------------------------------------------------
// Kernel 3: grouped-expert linear -> nbbf (bf16).
// ---------------------------------------------------------------------------
__global__ __launch_bounds__(256) void k_dlp(const float* __restrict__ hval,
                                             const float* __restrict__ dlp_lw,
                                             const float* __restrict__ dlp_lb,
                                             unsigned short* __restrict__ nbbf){
  const int et = blockIdx.x;
  const int n  = blockIdx.y;
  const int tid = threadIdx.x;
  __shared__ float hs[GG][GG*KK];
  for(int i = tid; i < GG*GG*KK; i += 256){
    const int g = i / (GG*KK), tt = i % (GG*KK);
    const int m = tt / KK, kq = tt % KK;
    hs[g][tt] = hval[(size_t)(((n*GG + m)*KK) + kq)*GG + g];
  }
  __syncthreads();
  const int h = tid >> 7, c = tid & 127;
  const int e = et*128 + c;
  float acc[4] = {0.f, 0.f, 0.f, 0.f};
#pragma unroll 4
  for(int k = 0; k < GG*KK; k++){
    const float w = dlp_lw[(size_t)k*EE + e];
#pragma unroll
    for(int rr = 0; rr < 4; rr++) acc[rr] += hs[h*4 + rr][k] * w;
  }
  const float lb = dlp_lb[e];
#pragma unroll
  for(int rr = 0; rr < 4; rr++)
    nbbf[(size_t)(n*GG + h*4 + rr)*EE + e] = f2bf(acc[rr] + lb);
}

// ---------------------------------------------------------------------------
// Kernel 4: l2-normalize nbbf rows in place (bf16).
// ---------------------------------------------------------------------------
__global__ __launch_bounds__(256) void k_l2nb(unsigned short* __restrict__ nbbf){
  const int b = blockIdx.x, t = threadIdx.x;
  uint4* p = (uint4*)(nbbf + (size_t)b*EE);
  uint4 u = p[t];
  unsigned short* us = (unsigned short*)&u;
  float f[8]; float ss = 0.f;
#pragma unroll
  for(int j = 0; j < 8; j++){ f[j] = bf2f(us[j]); ss += f[j]*f[j]; }
#pragma unroll
  for(int off = 32; off > 0; off >>= 1) ss += __shfl_down(ss, off);
  __shared__ float red[4];
  __shared__ float s_rn;
  if((t & 63) == 0) red[t >> 6] = ss;
  __syncthreads();
  if(t == 0) s_rn = 1.0f / (sqrtf(red[0] + red[1] + red[2] + red[3]) + 1e-8f);
  __syncthreads();
  const float rn = s_rn;
#pragma unroll
  for(int j = 0; j < 8; j++) us[j] = f2bf(f[j]*rn);
  p[t] = u;
}

// ---------------------------------------------------------------------------
// Kernel 5: weight transpose+convert: src[K][N] f32 -> dst[N][K] bf16.
// ---------------------------------------------------------------------------
__global__ __launch_bounds__(256) void k_wcvt(const float* __restrict__ src,
                                              unsigned short* __restrict__ dst,
                                              int Kd, int Nd){
  __shared__ float tile[32][33];
  const int n0 = blockIdx.x*32, k0 = blockIdx.y*32;
  const int r = threadIdx.x >> 3, c4 = (threadIdx.x & 7)*4;
  const float4 v = *(const float4*)(src + (size_t)(k0 + r)*Nd + n0 + c4);
  tile[r][c4+0] = v.x; tile[r][c4+1] = v.y; tile[r][c4+2] = v.z; tile[r][c4+3] = v.w;
  __syncthreads();
  ushort4 u;
  u.x = f2bf(tile[c4+0][r]); u.y = f2bf(tile[c4+1][r]);
  u.z = f2bf(tile[c4+2][r]); u.w = f2bf(tile[c4+3][r]);
  *(ushort4*)(dst + (size_t)(n0 + r)*Kd + k0 + c4) = u;
}

// ---------------------------------------------------------------------------
// Kernel 6: MFMA bf16 GEMM, 256x256 tile, BK=64, 8 waves (2Mx4N), double-
// buffered 128KiB LDS, TWO-PHASE K-step with counted per-phase vmcnt
// (unchanged from R5).
// POOL epilogue (NEW): two-level max-pool reduction — per-thread segmented
// max flushed into LDS pool[nseg][256] via ds_max_u32 on fkeys, then one
// coalesced pass of <=nseg*256 global atomicMax per block (consecutive tids
// -> consecutive cols). ~4x fewer global atomics, fully coalesced.
// ---------------------------------------------------------------------------
template<int KD, int ND, bool POOL, bool STATS, int NBX>
__global__ __launch_bounds__(512, 2) void k_mgemm(const unsigned short* __restrict__ A,
                                                  const unsigned short* __restrict__ Bt,
                                                  const float* __restrict__ bias,
                                                  unsigned short* __restrict__ obf,
                                                  const int* __restrict__ lensk,
                                                  unsigned* __restrict__ pkey,
                                                  float* __restrict__ psum,
                                                  float* __restrict__ psq){
  __shared__ short S[2][2][256*64];   // [buf][A|B][row*64+col] = 128 KiB
  const int tid  = threadIdx.x;
  const int wave = tid >> 6, lane = tid & 63;
  const int wr = wave >> 2, wc = wave & 3;        // 2M x 4N waves
  const int lrow = lane & 15, kg = lane >> 4;

  const int nwg = gridDim.x, cpx = nwg >> 3;      // grid % 8 == 0
  const int bid = (blockIdx.x & 7)*cpx + (blockIdx.x >> 3);
  const int bx = bid % NBX, by = bid / NBX;
  const int m0 = by*256, n0 = bx*256;

  const unsigned short* Ab = A  + (size_t)m0*KD;
  const unsigned short* Bb = Bt + (size_t)n0*KD;

  // one chunk = 64 rows x 64 k, 1 gload_lds x 16B per thread
#define STG_A(tt, p, c) { \
  const int i_ = tid + (c)*512; const int r_ = i_ >> 3; \
  const int g_ = (i_ & 7) ^ (r_ & 7); \
  __builtin_amdgcn_global_load_lds((gu32*)(Ab + (size_t)r_*KD + (tt)*64 + g_*8), \
                                   (lu32*)(&S[p][0][i_*8]), 16, 0, 0); }
#define STG_B(tt, p, c) { \
  const int i_ = tid + (c)*512; const int r_ = i_ >> 3; \
  const int g_ = (i_ & 7) ^ (r_ & 7); \
  __builtin_amdgcn_global_load_lds((gu32*)(Bb + (size_t)r_*KD + (tt)*64 + g_*8), \
                                   (lu32*)(&S[p][1][i_*8]), 16, 0, 0); }

  f32x4 acc[8][4] = {};
  const int NT = KD/64;

  // prologue: tile 0, in need-first order (A0,A2,B0..B3, then A1,A3)
  STG_A(0, 0, 0) STG_A(0, 0, 2)
  STG_B(0, 0, 0) STG_B(0, 0, 1) STG_B(0, 0, 2) STG_B(0, 0, 3)
  STG_A(0, 0, 1) STG_A(0, 0, 3)

  const int arow = wr*128 + lrow;     // + m*16
  const int brow = wc*64  + lrow;     // + n*16  (16|stride => row&7 == lrow&7)
  const int gx0 = ((0*4 + kg) ^ (lrow & 7))*8;   // swizzled granule, kk=0
  const int gx1 = ((1*4 + kg) ^ (lrow & 7))*8;   // swizzled granule, kk=1

  for(int t = 0; t < NT; t++){
    const int p = t & 1;
    const short* Abuf = &S[p][0][0];
    const short* Bbuf = &S[p][1][0];

    // ---------------- Phase 1 ----------------
    asm volatile("s_waitcnt vmcnt(2)" ::: "memory");   // t's A0,A2,B0..B3 landed
    __builtin_amdgcn_s_barrier();
    asm volatile("" ::: "memory");
    if(t + 1 < NT){
      STG_A(t+1, p^1, 0) STG_A(t+1, p^1, 2)
      STG_B(t+1, p^1, 0) STG_B(t+1, p^1, 1) STG_B(t+1, p^1, 2) STG_B(t+1, p^1, 3)
    }
    bf16x8 bg0[4], bg1[4], af[4];
#pragma unroll
    for(int n = 0; n < 4; n++){
      bg0[n] = *(const bf16x8*)(Bbuf + (brow + n*16)*64 + gx0);
      bg1[n] = *(const bf16x8*)(Bbuf + (brow + n*16)*64 + gx1);
    }
#pragma unroll
    for(int m = 0; m < 4; m++)
      af[m] = *(const bf16x8*)(Abuf + (arow + m*16)*64 + gx0);
    __builtin_amdgcn_s_setprio(1);
#pragma unroll
    for(int m = 0; m < 4; m++)
#pragma unroll
      for(int n = 0; n < 4; n++)
        acc[m][n] = __builtin_amdgcn_mfma_f32_16x16x32_bf16(af[m], bg0[n], acc[m][n], 0, 0, 0);
#pragma unroll
    for(int m = 0; m < 4; m++)
      af[m] = *(const bf16x8*)(Abuf + (arow + m*16)*64 + gx1);
#pragma unroll
    for(int m = 0; m < 4; m++)
#pragma unroll
      for(int n = 0; n < 4; n++)
        acc[m][n] = __builtin_amdgcn_mfma_f32_16x16x32_bf16(af[m], bg1[n], acc[m][n], 0, 0, 0);
    __builtin_amdgcn_s_setprio(0);

    // ---------------- Phase 2 ----------------
    if(t + 1 < NT) asm volatile("s_waitcnt vmcnt(6)" ::: "memory");  // t's A1,A3 landed
    else           asm volatile("s_waitcnt vmcnt(0)" ::: "memory");
    __builtin_amdgcn_s_barrier();
    asm volatile("" ::: "memory");
    if(t + 1 < NT){ STG_A(t+1, p^1, 1) STG_A(t+1, p^1, 3) }
#pragma unroll
    for(int m = 0; m < 4; m++)
      af[m] = *(const bf16x8*)(Abuf + (arow + 64 + m*16)*64 + gx0);
    __builtin_amdgcn_s_setprio(1);
#pragma unroll
    for(int m = 0; m < 4; m++)
#pragma unroll
      for(int n = 0; n < 4; n++)
        acc[4+m][n] = __builtin_amdgcn_mfma_f32_16x16x32_bf16(af[m], bg0[n], acc[4+m][n], 0, 0, 0);
#pragma unroll
    for(int m = 0; m < 4; m++)
      af[m] = *(const bf16x8*)(Abuf + (arow + 64 + m*16)*64 + gx1);
#pragma unroll
    for(int m = 0; m < 4; m++)
#pragma unroll
      for(int n = 0; n < 4; n++)
        acc[4+m][n] = __builtin_amdgcn_mfma_f32_16x16x32_bf16(af[m], bg1[n], acc[4+m][n], 0, 0, 0);
    __builtin_amdgcn_s_setprio(0);
  }
#undef STG_A
#undef STG_B

  if constexpr (!POOL){
    const int colb = n0 + wc*64 + lrow;
#pragma unroll
    for(int n = 0; n < 4; n++){
      const float bb = bias[colb + n*16];
      if constexpr (STATS){
        float sv = 0.f, qv = 0.f;
#pragma unroll
        for(int m = 0; m < 8; m++)
#pragma unroll
          for(int r = 0; r < 4; r++){
            const float v = acc[m][n][r] + bb; sv += v; qv += v*v;
          }
        sv += __shfl_xor(sv, 16); sv += __shfl_xor(sv, 32);
        qv += __shfl_xor(qv, 16); qv += __shfl_xor(qv, 32);
        if(lane < 16){
          psum[(size_t)(by*2 + wr)*ND + colb + n*16] = sv;
          psq [(size_t)(by*2 + wr)*ND + colb + n*16] = qv;
        }
      }
#pragma unroll
      for(int m = 0; m < 8; m++){
        const int row = m0 + wr*128 + m*16 + kg*4;
#pragma unroll
        for(int r = 0; r < 4; r++)
          obf[(size_t)(row + r)*ND + colb + n*16] = f2bf(acc[m][n][r] + bb);
      }
    }
  } else {
    // ---- two-level segmented max-pool: regs -> LDS (ds_max_u32) -> global --
    __syncthreads();                               // all waves' S reads retired
    unsigned* pool = (unsigned*)&S[0][0][0];       // [nseg][256] fkeys, <=10KB
    const int b0 = m0 / KK;
    const int b1 = (m0 + 255) / KK;
    const int nseg = b1 - b0 + 1;                  // <= 10
    for(int i = tid; i < nseg*256; i += 512) pool[i] = 0x007FFFFFu;  // fkey(-inf)
    __syncthreads();
    const int lcol = wc*64 + lrow;                 // + n*16
    {
      int cur_b = -1;
      float mx[4];
#pragma unroll
      for(int m = 0; m < 8; m++){
#pragma unroll
        for(int r = 0; r < 4; r++){
          const int row = m0 + wr*128 + m*16 + kg*4 + r;
          const int bt = row / KK;
          const int rr = row - bt*KK;
          if(bt != cur_b){
            if(cur_b >= 0){
#pragma unroll
              for(int n = 0; n < 4; n++)
                atomicMax(&pool[(cur_b - b0)*256 + lcol + n*16], fkey(mx[n]));
            }
            cur_b = bt;
#pragma unroll
            for(int n = 0; n < 4; n++) mx[n] = -INFINITY;
          }
          if(rr < lensk[bt]){
#pragma unroll
            for(int n = 0; n < 4; n++) mx[n] = fmaxf(mx[n], acc[m][n][r]);
          }
        }
      }
#pragma unroll
      for(int n = 0; n < 4; n++)
        atomicMax(&pool[(cur_b - b0)*256 + lcol + n*16], fkey(mx[n]));
    }
    __syncthreads();
    for(int e = tid; e < nseg*256; e += 512){
      const int seg = e >> 8, col = e & 255;
      atomicMax(&pkey[(size_t)(b0 + seg)*ND + n0 + col], pool[e]);
    }
  }
}

// ---------------------------------------------------------------------------
// Kernel 7: BN finalize from GEMM1's fused partials (120 row-groups).
// ---------------------------------------------------------------------------
__global__ __launch_bounds__(256) void k_bnfin(const float* __restrict__ psum,
                                               const float* __restrict__ psq,
                                               const float* __restrict__ bn_g,
                                               const float* __restrict__ bn_b,
                                               float* __restrict__ sc,
                                               float* __restrict__ sh){
  const int c = blockIdx.x*256 + threadIdx.x;
  float s = 0.f, q = 0.f;
  for(int i = 0; i < 120; i++){ s += psum[(size_t)i*HH + c]; q += psq[(size_t)i*HH + c]; }
  const float mu  = s * (1.0f/NROWS);
  const float var = q * (1.0f/NROWS) - mu*mu;
  const float sv  = bn_g[c] / sqrtf(var + 1e-5f);
  sc[c] = sv;
  sh[c] = bn_b[c] - mu*sv;
}

// ---------------------------------------------------------------------------
// Kernel 8: BN+ReLU in place on x1 (bf16) + pkey init (overlay region
// psum/psq/w1t/hval/idx is dead by now; lensk lies outside the overlay).
// ---------------------------------------------------------------------------
__global__ __launch_bounds__(256) void k_bnrelu(unsigned short* __restrict__ x1,
                                                const float* __restrict__ sc,
                                                const float* __restrict__ sh,
                                                unsigned* __restrict__ pkey){
  const size_t i = (size_t)blockIdx.x*256 + threadIdx.x;   // chunk of 8 bf16
  const int c0 = (int)((i*8) & (HH-1));
  uint4 u = ((uint4*)x1)[i];
  unsigned short* us = (unsigned short*)&u;
  const float4 s0 = *(const float4*)(sc + c0), s1 = *(const float4*)(sc + c0 + 4);
  const float4 h0 = *(const float4*)(sh + c0), h1 = *(const float4*)(sh + c0 + 4);
  const float scv[8] = {s0.x,s0.y,s0.z,s0.w,s1.x,s1.y,s1.z,s1.w};
  const float shv[8] = {h0.x,h0.y,h0.z,h0.w,h1.x,h1.y,h1.z,h1.w};
#pragma unroll
  for(int j = 0; j < 8; j++)
    us[j] = f2bf(fmaxf(bf2f(us[j])*scv[j] + shv[j], 0.f));
  ((uint4*)x1)[i] = u;
  if(blockIdx.x < 1024)
    ((uint4*)pkey)[blockIdx.x*256 + threadIdx.x] =
        make_uint4(0x007FFFFFu, 0x007FFFFFu, 0x007FFFFFu, 0x007FFFFFu);  // key(-inf)
}

// ---------------------------------------------------------------------------
// Kernel 9: finalize output.
// ---------------------------------------------------------------------------
__global__ __launch_bounds__(256) void k_final(const unsigned* __restrict__ pkey,
                                               const float* __restrict__ b2,
                                               const unsigned short* __restrict__ nbbf,
                                               float* __restrict__ out){
  const size_t i = (size_t)blockIdx.x*256 + threadIdx.x;   // per 4 elems
  const int c0 = (int)((i*4) & (EE-1));
  const uint4 k = ((const uint4*)pkey)[i];
  const ushort4 nb4 = ((const ushort4*)nbbf)[i];
  const float4 b = *(const float4*)(b2 + c0);
  float4 o;
  o.x = fdec(k.x) + b.x + bf2f(nb4.x);
  o.y = fdec(k.y) + b.y + bf2f(nb4.y);
  o.z = fdec(k.z) + b.z + bf2f(nb4.z);
  o.w = fdec(k.w) + b.w + bf2f(nb4.w);
  ((float4*)out)[i] = o;
}

// ---------------------------------------------------------------------------
extern "C" void kernel_launch(void* const* d_in, const int* in_sizes, int n_in,
                              void* d_out, int out_size, void* d_ws, size_t ws_size,
                              hipStream_t stream){
  const float* features = (const float*)d_in[0];
  const float* atten    = (const float*)d_in[1];
  const int*   text     = (const int*)  d_in[2];
  const float* dlp_w    = (const float*)d_in[4];
  const float* dlp_b    = (const float*)d_in[5];
  const float* dlp_lw   = (const float*)d_in[6];
  const float* dlp_lb   = (const float*)d_in[7];
  const float* w1       = (const float*)d_in[8];
  const float* b1       = (const float*)d_in[9];
  const float* bn_g     = (const float*)d_in[10];
  const float* bn_b     = (const float*)d_in[11];
  const float* w2       = (const float*)d_in[12];
  const float* b2       = (const float*)d_in[13];
  float* out = (float*)d_out;

  // Workspace layout with lifetime aliasing:
  char* ws = (char*)d_ws;
  float*          psum   = (float*)(ws + 0);               //   491,520 (120x1024)
  float*          psq    = (float*)(ws + 983040);          //   491,520
  unsigned short* w1t    = (unsigned short*)(ws + 1966080);// 1,048,576
  float*          hval   = (float*)(ws + 3014656);         //   491,520
  int*            idx    = (int*)(ws + 3506176);           //    61,440
  unsigned*       pkey   = (unsigned*)(ws + 0);            // 4,194,304 (overlay, live from k_bnrelu on)
  int*            lensk  = (int*)(ws + 4194304);           //     2,048
  float*          sc     = (float*)(ws + 4196352);         //     4,096
  float*          sh     = (float*)(ws + 4200448);         //     4,096
  unsigned short* nfeats = (unsigned short*)(ws + 4204544);// 15,728,640
  unsigned short* w2t    = (unsigned short*)(ws + 4204544);// 4,194,304 (overlays nfeats after gemm1)
  unsigned short* x1     = (unsigned short*)(ws + 19933184);//31,457,280
  unsigned short* nbbf   = (unsigned short*)(ws + 51390464);// 2,097,152

  k_wcvt<<<dim3(HH/32, DD/32), 256, 0, stream>>>(w1, w1t, DD, HH);
  k_prep<<<BS, 64, 0, stream>>>(atten, text, idx, lensk);
  k_gather<<<NROWS, 128, 0, stream>>>(features, dlp_w, dlp_b, idx, nfeats, hval);
  k_dlp<<<dim3(16, NG), 256, 0, stream>>>(hval, dlp_lw, dlp_lb, nbbf);
  k_l2nb<<<BS, 256, 0, stream>>>(nbbf);
  k_mgemm<DD, HH, false, true, HH/256><<<(HH/256)*(NROWS/256), 512, 0, stream>>>(
      nfeats, w1t, b1, x1, nullptr, nullptr, psum, psq);
  k_wcvt<<<dim3(EE/32, HH/32), 256, 0, stream>>>(w2, w2t, HH, EE);   // nfeats dead now
  k_bnfin<<<4, 256, 0, stream>>>(psum, psq, bn_g, bn_b, sc, sh);
  k_bnrelu<<<(NROWS*HH/8)/256, 256, 0, stream>>>(x1, sc, sh, pkey);
  k_mgemm<HH, EE, true, false, EE/256><<<(EE/256)*(NROWS/256), 512, 0, stream>>>(
      x1, w2t, nullptr, nullptr, lensk, pkey, nullptr, nullptr);
  k_final<<<(BS*EE/4)/256, 256, 0, stream>>>(pkey, b2, nbbf, out);
}